// Round 1
// baseline (874.457 us; speedup 1.0000x reference)
//
#include <hip/hip_runtime.h>
#include <hip/hip_bf16.h>

// ---------------------------------------------------------------------------
// EGNN layer, fused bf16-MFMA implementation.
//   edge net : [E,544]x[544,256] -> SiLU -> x[256,256] -> +b -> LN -> edge_msg
//   coord net: [E,256]x[256,128] -> SiLU -> dot(cn_w2) -> tanh -> +- atomic pos
//   node net : segment_sum(edge_msg, col) ; [N,512]x[512,256]->SiLU->x[256,256]->LN
// Weights are pre-sliced into [K/32][N][40] bf16 (40 = 32 data + 8 pad so that
// B-fragment ds_read_b128 is conflict-spread) so every GEMM k-step stages a
// linear 20KB slice via global_load_lds width=16.
// ---------------------------------------------------------------------------

#define NN 16384
#define EE 262144
#define HH 256
#define RR 32

typedef __bf16 bf16x8 __attribute__((ext_vector_type(8)));
typedef float f32x4 __attribute__((ext_vector_type(4)));

typedef const void __attribute__((address_space(1)))* gas_ptr;
typedef void __attribute__((address_space(3)))* las_ptr;

__device__ __forceinline__ void gload16(const void* g, void* l) {
  __builtin_amdgcn_global_load_lds((gas_ptr)g, (las_ptr)l, 16, 0, 0);
}

__device__ __forceinline__ float silu_f(float x) { return x / (1.0f + __expf(-x)); }

__device__ __forceinline__ unsigned short bf_bits(float x) {
  union { __hip_bfloat16 b; unsigned short u; } v;
  v.b = __float2bfloat16(x);
  return v.u;
}

// ---------------- prep ----------------
__global__ __launch_bounds__(256) void conv_h_kernel(const float* __restrict__ src,
                                                     __hip_bfloat16* __restrict__ dst,
                                                     int n4) {
  int i = blockIdx.x * 256 + threadIdx.x;
  if (i >= n4) return;
  float4 v = ((const float4*)src)[i];
  __hip_bfloat16* d = dst + (size_t)i * 4;
  d[0] = __float2bfloat16(v.x);
  d[1] = __float2bfloat16(v.y);
  d[2] = __float2bfloat16(v.z);
  d[3] = __float2bfloat16(v.w);
}

// W [K][Ncols] f32 row-major -> k-slices: out[(s*Ncols+n)*40 + kk] = W[(s*32+kk)*Ncols+n]
__global__ __launch_bounds__(256) void slice_w_kernel(const float* __restrict__ W,
                                                      __hip_bfloat16* __restrict__ out,
                                                      int K, int Ncols) {
  int i = blockIdx.x * 256 + threadIdx.x;
  if (i >= K * Ncols) return;
  int kk = i & 31;
  int sn = i >> 5;
  int n = sn % Ncols;
  int s = sn / Ncols;
  out[((size_t)(s * Ncols + n)) * 40 + kk] =
      __float2bfloat16(W[((size_t)(s * 32 + kk)) * Ncols + n]);
}

// ---------------- radial basis ----------------
__global__ __launch_bounds__(256) void radial_kernel(const int* __restrict__ ei,
                                                     const float* __restrict__ pos,
                                                     const float* __restrict__ rbw1,
                                                     const float* __restrict__ rbb1,
                                                     const float* __restrict__ rbw2,
                                                     const float* __restrict__ rbb2,
                                                     __hip_bfloat16* __restrict__ radial) {
  int e = blockIdx.x * 256 + threadIdx.x;
  if (e >= EE) return;
  int r = ei[e], c = ei[EE + e];
  float dx = pos[c * 3 + 0] - pos[r * 3 + 0] + 1e-8f;
  float dy = pos[c * 3 + 1] - pos[r * 3 + 1] + 1e-8f;
  float dz = pos[c * 3 + 2] - pos[r * 3 + 2] + 1e-8f;
  float d = sqrtf(dx * dx + dy * dy + dz * dz);
  float r1[RR];
#pragma unroll
  for (int j = 0; j < RR; ++j) {
    float x = d * rbw1[j] + rbb1[j];
    r1[j] = silu_f(x);
  }
#pragma unroll 4
  for (int k = 0; k < RR; ++k) {
    float acc = rbb2[k];
#pragma unroll
    for (int j = 0; j < RR; ++j) acc += r1[j] * rbw2[j * RR + k];
    radial[(size_t)e * RR + k] = __float2bfloat16(acc);
  }
}

// ---------------- CSR build (col) ----------------
__global__ __launch_bounds__(256) void count_kernel(const int* __restrict__ ei,
                                                    int* __restrict__ counts) {
  int e = blockIdx.x * 256 + threadIdx.x;
  if (e >= EE) return;
  atomicAdd(&counts[ei[EE + e]], 1);
}

__global__ __launch_bounds__(1024) void scan_kernel(const int* __restrict__ counts,
                                                    int* __restrict__ offs,
                                                    int* __restrict__ cursor) {
  __shared__ int buf[1024];
  __shared__ int carry;
  int tid = threadIdx.x;
  if (tid == 0) carry = 0;
  __syncthreads();
  for (int base = 0; base < NN; base += 1024) {
    int v = counts[base + tid];
    buf[tid] = v;
    __syncthreads();
    for (int s = 1; s < 1024; s <<= 1) {
      int x = (tid >= s) ? buf[tid - s] : 0;
      __syncthreads();
      buf[tid] += x;
      __syncthreads();
    }
    int incl = buf[tid];
    int c = carry;
    __syncthreads();
    offs[base + tid] = c + incl - v;
    cursor[base + tid] = c + incl - v;
    if (tid == 1023) carry = c + incl;
    __syncthreads();
  }
  if (tid == 0) offs[NN] = carry;
}

__global__ __launch_bounds__(256) void scatter_kernel(const int* __restrict__ ei,
                                                      int* __restrict__ cursor,
                                                      int* __restrict__ elist) {
  int e = blockIdx.x * 256 + threadIdx.x;
  if (e >= EE) return;
  int c = ei[EE + e];
  int p = atomicAdd(&cursor[c], 1);
  elist[p] = e;
}

// ---------------- fused edge kernel ----------------
// 64 edges per block, 256 threads (4 waves). Wave w covers output cols [64w,64w+64).
__global__ __launch_bounds__(256) void edge_kernel(
    const __hip_bfloat16* __restrict__ hb, const int* __restrict__ ei,
    const float* __restrict__ pos, const __hip_bfloat16* __restrict__ W1S,
    const float* __restrict__ en_b1, const __hip_bfloat16* __restrict__ W2S,
    const float* __restrict__ en_b2, const float* __restrict__ en_g,
    const float* __restrict__ en_bt, const __hip_bfloat16* __restrict__ CW1S,
    const float* __restrict__ cn_b1, const float* __restrict__ cn_w2,
    const float* __restrict__ cn_b2, const __hip_bfloat16* __restrict__ radial,
    __hip_bfloat16* __restrict__ emsg, float* __restrict__ pos_out) {
  __shared__ __align__(16) __hip_bfloat16 Abuf[64 * 552];   // [64][544+8] gathered edge_feat
  __shared__ __align__(16) __hip_bfloat16 Wbuf[256 * 40];   // one weight k-slice
  __shared__ __align__(16) __hip_bfloat16 A2buf[64 * 264];  // hidden / edge_msg tile
  __shared__ int srow[64], scol[64];
  __shared__ float relbuf[64][3];
  __shared__ float red[4][64], redsq[4][64];
  __shared__ float mvbuf[64][2];
  __shared__ float gbuf[HH], btbuf[HH], cb1f[128], cw2f[128];

  const int tid = threadIdx.x;
  const int w = tid >> 6;
  const int l = tid & 63;
  const int r = l & 15;
  const int g = l >> 4;
  const int e0 = blockIdx.x * 64;

  gbuf[tid] = en_g[tid];
  btbuf[tid] = en_bt[tid];
  if (tid < 128) {
    cb1f[tid] = cn_b1[tid];
    cw2f[tid] = cn_w2[tid];
  }
  if (tid < 64) {
    int e = e0 + tid;
    int rr = ei[e], cc = ei[EE + e];
    srow[tid] = rr;
    scol[tid] = cc;
    relbuf[tid][0] = pos[cc * 3 + 0] - pos[rr * 3 + 0];
    relbuf[tid][1] = pos[cc * 3 + 1] - pos[rr * 3 + 1];
    relbuf[tid][2] = pos[cc * 3 + 2] - pos[rr * 3 + 2];
  }
  __syncthreads();

  // gather A tile: cols [0,256)=h[row], [256,512)=h[col], [512,544)=radial
#pragma unroll
  for (int it = 0; it < 16; ++it) {
    int ch = it * 256 + tid;  // 4096 chunks of 16B
    int i = ch >> 6;
    int half = (ch >> 5) & 1;
    int c = ch & 31;
    int node = half ? scol[i] : srow[i];
    float4 v = *(const float4*)(hb + (size_t)node * HH + c * 8);
    *(float4*)(Abuf + i * 552 + half * 256 + c * 8) = v;
  }
  {
    int e = tid >> 2, part = tid & 3;
    float4 v = *(const float4*)(radial + (size_t)(e0 + e) * RR + part * 8);
    *(float4*)(Abuf + e * 552 + 512 + part * 8) = v;
  }

  f32x4 acc[4][4];
#pragma unroll
  for (int a = 0; a < 4; ++a)
#pragma unroll
    for (int b = 0; b < 4; ++b) acc[a][b] = (f32x4){0.f, 0.f, 0.f, 0.f};

  // ---- GEMM1: K=544 ----
  for (int ks = 0; ks < 17; ++ks) {
    const __hip_bfloat16* S = W1S + (size_t)ks * (HH * 40);
    for (int c = w; c < 20; c += 4)
      gload16((const char*)S + (c << 10) + (l << 4), (char*)Wbuf + (c << 10));
    __syncthreads();
    bf16x8 af[4], bfr[4];
#pragma unroll
    for (int fm = 0; fm < 4; ++fm)
      af[fm] = *(const bf16x8*)(Abuf + (fm * 16 + r) * 552 + ks * 32 + g * 8);
#pragma unroll
    for (int fn = 0; fn < 4; ++fn)
      bfr[fn] = *(const bf16x8*)(Wbuf + (w * 64 + fn * 16 + r) * 40 + g * 8);
#pragma unroll
    for (int fm = 0; fm < 4; ++fm)
#pragma unroll
      for (int fn = 0; fn < 4; ++fn)
        acc[fm][fn] =
            __builtin_amdgcn_mfma_f32_16x16x32_bf16(af[fm], bfr[fn], acc[fm][fn], 0, 0, 0);
    __syncthreads();
  }

  // bias + SiLU -> A2 (bf16)
#pragma unroll
  for (int fm = 0; fm < 4; ++fm) {
#pragma unroll
    for (int fn = 0; fn < 4; ++fn) {
      int col = w * 64 + fn * 16 + r;
      float b1 = en_b1[col];
#pragma unroll
      for (int q = 0; q < 4; ++q) {
        int row = fm * 16 + g * 4 + q;
        A2buf[row * 264 + col] = __float2bfloat16(silu_f(acc[fm][fn][q] + b1));
      }
    }
  }
  __syncthreads();

  // ---- GEMM2: K=256 ----
#pragma unroll
  for (int a = 0; a < 4; ++a)
#pragma unroll
    for (int b = 0; b < 4; ++b) acc[a][b] = (f32x4){0.f, 0.f, 0.f, 0.f};
  for (int ks = 0; ks < 8; ++ks) {
    const __hip_bfloat16* S = W2S + (size_t)ks * (HH * 40);
    for (int c = w; c < 20; c += 4)
      gload16((const char*)S + (c << 10) + (l << 4), (char*)Wbuf + (c << 10));
    __syncthreads();
    bf16x8 af[4], bfr[4];
#pragma unroll
    for (int fm = 0; fm < 4; ++fm)
      af[fm] = *(const bf16x8*)(A2buf + (fm * 16 + r) * 264 + ks * 32 + g * 8);
#pragma unroll
    for (int fn = 0; fn < 4; ++fn)
      bfr[fn] = *(const bf16x8*)(Wbuf + (w * 64 + fn * 16 + r) * 40 + g * 8);
#pragma unroll
    for (int fm = 0; fm < 4; ++fm)
#pragma unroll
      for (int fn = 0; fn < 4; ++fn)
        acc[fm][fn] =
            __builtin_amdgcn_mfma_f32_16x16x32_bf16(af[fm], bfr[fn], acc[fm][fn], 0, 0, 0);
    __syncthreads();
  }

  // + b2, then LayerNorm stats (rows distributed: row = fm*16 + g*4 + q)
#pragma unroll
  for (int fn = 0; fn < 4; ++fn) {
    float b2 = en_b2[w * 64 + fn * 16 + r];
#pragma unroll
    for (int fm = 0; fm < 4; ++fm)
#pragma unroll
      for (int q = 0; q < 4; ++q) acc[fm][fn][q] += b2;
  }
#pragma unroll
  for (int fm = 0; fm < 4; ++fm) {
#pragma unroll
    for (int q = 0; q < 4; ++q) {
      float s = acc[fm][0][q] + acc[fm][1][q] + acc[fm][2][q] + acc[fm][3][q];
      float sq = acc[fm][0][q] * acc[fm][0][q] + acc[fm][1][q] * acc[fm][1][q] +
                 acc[fm][2][q] * acc[fm][2][q] + acc[fm][3][q] * acc[fm][3][q];
#pragma unroll
      for (int m = 1; m < 16; m <<= 1) {
        s += __shfl_xor(s, m, 64);
        sq += __shfl_xor(sq, m, 64);
      }
      if (r == 0) {
        red[w][fm * 16 + g * 4 + q] = s;
        redsq[w][fm * 16 + g * 4 + q] = sq;
      }
    }
  }
  __syncthreads();
  if (tid < 64) {
    float s = red[0][tid] + red[1][tid] + red[2][tid] + red[3][tid];
    float sq = redsq[0][tid] + redsq[1][tid] + redsq[2][tid] + redsq[3][tid];
    float mean = s * (1.0f / HH);
    float var = sq * (1.0f / HH) - mean * mean;
    mvbuf[tid][0] = mean;
    mvbuf[tid][1] = rsqrtf(var + 1e-5f);
  }
  __syncthreads();
#pragma unroll
  for (int fm = 0; fm < 4; ++fm) {
#pragma unroll
    for (int fn = 0; fn < 4; ++fn) {
      int col = w * 64 + fn * 16 + r;
      float gg = gbuf[col], bb = btbuf[col];
#pragma unroll
      for (int q = 0; q < 4; ++q) {
        int row = fm * 16 + g * 4 + q;
        float x = (acc[fm][fn][q] - mvbuf[row][0]) * mvbuf[row][1] * gg + bb;
        A2buf[row * 264 + col] = __float2bfloat16(x);
      }
    }
  }
  __syncthreads();

  // coalesced edge_msg store (LDS -> global)
#pragma unroll
  for (int it = 0; it < 8; ++it) {
    int ch = it * 256 + tid;  // 2048 chunks of 16B
    int row = ch >> 5, c = ch & 31;
    float4 v = *(const float4*)(A2buf + row * 264 + c * 8);
    *(float4*)(emsg + (size_t)(e0 + row) * HH + c * 8) = v;
  }

  // ---- coord head: [64,256]x[256,128] -> SiLU -> dot cn_w2 -> tanh ----
  f32x4 c3[4][2];
#pragma unroll
  for (int a = 0; a < 4; ++a)
#pragma unroll
    for (int b = 0; b < 2; ++b) c3[a][b] = (f32x4){0.f, 0.f, 0.f, 0.f};
  for (int ks = 0; ks < 8; ++ks) {
    const __hip_bfloat16* S = CW1S + (size_t)ks * (128 * 40);
    for (int c = w; c < 10; c += 4)
      gload16((const char*)S + (c << 10) + (l << 4), (char*)Wbuf + (c << 10));
    __syncthreads();
    bf16x8 af[4], bfr[2];
#pragma unroll
    for (int fm = 0; fm < 4; ++fm)
      af[fm] = *(const bf16x8*)(A2buf + (fm * 16 + r) * 264 + ks * 32 + g * 8);
#pragma unroll
    for (int fn = 0; fn < 2; ++fn)
      bfr[fn] = *(const bf16x8*)(Wbuf + (w * 32 + fn * 16 + r) * 40 + g * 8);
#pragma unroll
    for (int fm = 0; fm < 4; ++fm)
#pragma unroll
      for (int fn = 0; fn < 2; ++fn)
        c3[fm][fn] =
            __builtin_amdgcn_mfma_f32_16x16x32_bf16(af[fm], bfr[fn], c3[fm][fn], 0, 0, 0);
    __syncthreads();
  }
  float* C1f = (float*)Abuf;  // reuse A-tile LDS as f32 [64][132]
#pragma unroll
  for (int fm = 0; fm < 4; ++fm) {
#pragma unroll
    for (int fn = 0; fn < 2; ++fn) {
      int n = w * 32 + fn * 16 + r;
      float b = cb1f[n];
#pragma unroll
      for (int q = 0; q < 4; ++q) {
        int row = fm * 16 + g * 4 + q;
        C1f[row * 132 + n] = silu_f(c3[fm][fn][q] + b);
      }
    }
  }
  __syncthreads();
  {
    int e = tid >> 2, q = tid & 3;
    float s = 0.f;
#pragma unroll
    for (int i = 0; i < 32; ++i) s += C1f[e * 132 + q * 32 + i] * cw2f[q * 32 + i];
    s += __shfl_xor(s, 1, 64);
    s += __shfl_xor(s, 2, 64);
    if (q == 0) {
      float wgt = tanhf(s + cn_b2[0]);
      float ax = relbuf[e][0], ay = relbuf[e][1], az = relbuf[e][2];
      int rr = srow[e], cc = scol[e];
      atomicAdd(&pos_out[rr * 3 + 0], -wgt * ax);
      atomicAdd(&pos_out[rr * 3 + 1], -wgt * ay);
      atomicAdd(&pos_out[rr * 3 + 2], -wgt * az);
      atomicAdd(&pos_out[cc * 3 + 0], wgt * ax);
      atomicAdd(&pos_out[cc * 3 + 1], wgt * ay);
      atomicAdd(&pos_out[cc * 3 + 2], wgt * az);
    }
  }
}

// ---------------- node_msg = segment_sum(edge_msg, col) via CSR ----------------
__global__ __launch_bounds__(256) void nodemsg_kernel(const int* __restrict__ offs,
                                                      const int* __restrict__ elist,
                                                      const __hip_bfloat16* __restrict__ emsg,
                                                      float* __restrict__ nmsg) {
  int wid = threadIdx.x >> 6, l = threadIdx.x & 63;
  int n = blockIdx.x * 4 + wid;
  float a0 = 0.f, a1 = 0.f, a2 = 0.f, a3 = 0.f;
  int b = offs[n], e2 = offs[n + 1];
  for (int idx = b; idx < e2; ++idx) {
    int e = elist[idx];
    const __hip_bfloat16* row = emsg + (size_t)e * HH;
    a0 += __bfloat162float(row[l]);
    a1 += __bfloat162float(row[l + 64]);
    a2 += __bfloat162float(row[l + 128]);
    a3 += __bfloat162float(row[l + 192]);
  }
  float* out = nmsg + (size_t)n * HH;
  out[l] = a0;
  out[l + 64] = a1;
  out[l + 128] = a2;
  out[l + 192] = a3;
}

// ---------------- fused node kernel ----------------
__global__ __launch_bounds__(256) void node_kernel(
    const __hip_bfloat16* __restrict__ hb, const float* __restrict__ nmsg,
    const __hip_bfloat16* __restrict__ NW1S, const float* __restrict__ nn_b1,
    const __hip_bfloat16* __restrict__ NW2S, const float* __restrict__ nn_b2,
    const float* __restrict__ nn_g, const float* __restrict__ nn_bt,
    float* __restrict__ out_h) {
  __shared__ __align__(16) __hip_bfloat16 Abuf[64 * 520];  // [64][512+8]
  __shared__ __align__(16) __hip_bfloat16 Wbuf[256 * 40];
  __shared__ __align__(16) __hip_bfloat16 A2buf[64 * 264];
  __shared__ float red[4][64], redsq[4][64];
  __shared__ float mvbuf[64][2];
  __shared__ float gbuf[HH], btbuf[HH];
  const int tid = threadIdx.x, w = tid >> 6, l = tid & 63, r = l & 15, g = l >> 4;
  const int n0 = blockIdx.x * 64;
  gbuf[tid] = nn_g[tid];
  btbuf[tid] = nn_bt[tid];
#pragma unroll
  for (int it = 0; it < 8; ++it) {  // h part (bf16, contiguous rows)
    int ch = it * 256 + tid;
    int i = ch >> 5, c = ch & 31;
    float4 v = *(const float4*)(hb + (size_t)(n0 + i) * HH + c * 8);
    *(float4*)(Abuf + i * 520 + c * 8) = v;
  }
#pragma unroll
  for (int it = 0; it < 16; ++it) {  // node_msg part (f32 -> bf16)
    int ch = it * 256 + tid;
    int i = ch >> 6, c = ch & 63;
    float4 v = *(const float4*)(nmsg + (size_t)(n0 + i) * HH + c * 4);
    ushort4 o;
    o.x = bf_bits(v.x);
    o.y = bf_bits(v.y);
    o.z = bf_bits(v.z);
    o.w = bf_bits(v.w);
    *(ushort4*)(Abuf + i * 520 + 256 + c * 4) = o;
  }

  f32x4 acc[4][4];
#pragma unroll
  for (int a = 0; a < 4; ++a)
#pragma unroll
    for (int b = 0; b < 4; ++b) acc[a][b] = (f32x4){0.f, 0.f, 0.f, 0.f};
  for (int ks = 0; ks < 16; ++ks) {  // K=512
    const __hip_bfloat16* S = NW1S + (size_t)ks * (HH * 40);
    for (int c = w; c < 20; c += 4)
      gload16((const char*)S + (c << 10) + (l << 4), (char*)Wbuf + (c << 10));
    __syncthreads();
    bf16x8 af[4], bfr[4];
#pragma unroll
    for (int fm = 0; fm < 4; ++fm)
      af[fm] = *(const bf16x8*)(Abuf + (fm * 16 + r) * 520 + ks * 32 + g * 8);
#pragma unroll
    for (int fn = 0; fn < 4; ++fn)
      bfr[fn] = *(const bf16x8*)(Wbuf + (w * 64 + fn * 16 + r) * 40 + g * 8);
#pragma unroll
    for (int fm = 0; fm < 4; ++fm)
#pragma unroll
      for (int fn = 0; fn < 4; ++fn)
        acc[fm][fn] =
            __builtin_amdgcn_mfma_f32_16x16x32_bf16(af[fm], bfr[fn], acc[fm][fn], 0, 0, 0);
    __syncthreads();
  }
#pragma unroll
  for (int fm = 0; fm < 4; ++fm) {
#pragma unroll
    for (int fn = 0; fn < 4; ++fn) {
      int col = w * 64 + fn * 16 + r;
      float b1 = nn_b1[col];
#pragma unroll
      for (int q = 0; q < 4; ++q) {
        int row = fm * 16 + g * 4 + q;
        A2buf[row * 264 + col] = __float2bfloat16(silu_f(acc[fm][fn][q] + b1));
      }
    }
  }
  __syncthreads();
#pragma unroll
  for (int a = 0; a < 4; ++a)
#pragma unroll
    for (int b = 0; b < 4; ++b) acc[a][b] = (f32x4){0.f, 0.f, 0.f, 0.f};
  for (int ks = 0; ks < 8; ++ks) {  // K=256
    const __hip_bfloat16* S = NW2S + (size_t)ks * (HH * 40);
    for (int c = w; c < 20; c += 4)
      gload16((const char*)S + (c << 10) + (l << 4), (char*)Wbuf + (c << 10));
    __syncthreads();
    bf16x8 af[4], bfr[4];
#pragma unroll
    for (int fm = 0; fm < 4; ++fm)
      af[fm] = *(const bf16x8*)(A2buf + (fm * 16 + r) * 264 + ks * 32 + g * 8);
#pragma unroll
    for (int fn = 0; fn < 4; ++fn)
      bfr[fn] = *(const bf16x8*)(Wbuf + (w * 64 + fn * 16 + r) * 40 + g * 8);
#pragma unroll
    for (int fm = 0; fm < 4; ++fm)
#pragma unroll
      for (int fn = 0; fn < 4; ++fn)
        acc[fm][fn] =
            __builtin_amdgcn_mfma_f32_16x16x32_bf16(af[fm], bfr[fn], acc[fm][fn], 0, 0, 0);
    __syncthreads();
  }
#pragma unroll
  for (int fn = 0; fn < 4; ++fn) {
    float b2 = nn_b2[w * 64 + fn * 16 + r];
#pragma unroll
    for (int fm = 0; fm < 4; ++fm)
#pragma unroll
      for (int q = 0; q < 4; ++q) acc[fm][fn][q] += b2;
  }
#pragma unroll
  for (int fm = 0; fm < 4; ++fm) {
#pragma unroll
    for (int q = 0; q < 4; ++q) {
      float s = acc[fm][0][q] + acc[fm][1][q] + acc[fm][2][q] + acc[fm][3][q];
      float sq = acc[fm][0][q] * acc[fm][0][q] + acc[fm][1][q] * acc[fm][1][q] +
                 acc[fm][2][q] * acc[fm][2][q] + acc[fm][3][q] * acc[fm][3][q];
#pragma unroll
      for (int m = 1; m < 16; m <<= 1) {
        s += __shfl_xor(s, m, 64);
        sq += __shfl_xor(sq, m, 64);
      }
      if (r == 0) {
        red[w][fm * 16 + g * 4 + q] = s;
        redsq[w][fm * 16 + g * 4 + q] = sq;
      }
    }
  }
  __syncthreads();
  if (tid < 64) {
    float s = red[0][tid] + red[1][tid] + red[2][tid] + red[3][tid];
    float sq = redsq[0][tid] + redsq[1][tid] + redsq[2][tid] + redsq[3][tid];
    float mean = s * (1.0f / HH);
    float var = sq * (1.0f / HH) - mean * mean;
    mvbuf[tid][0] = mean;
    mvbuf[tid][1] = rsqrtf(var + 1e-5f);
  }
  __syncthreads();
  float* Of = (float*)Abuf;  // reuse A-tile LDS as f32 [64][256] output stage
#pragma unroll
  for (int fm = 0; fm < 4; ++fm) {
#pragma unroll
    for (int fn = 0; fn < 4; ++fn) {
      int col = w * 64 + fn * 16 + r;
      float gg = gbuf[col], bb = btbuf[col];
#pragma unroll
      for (int q = 0; q < 4; ++q) {
        int row = fm * 16 + g * 4 + q;
        Of[row * 256 + col] = (acc[fm][fn][q] - mvbuf[row][0]) * mvbuf[row][1] * gg + bb;
      }
    }
  }
  __syncthreads();
#pragma unroll
  for (int it = 0; it < 16; ++it) {
    int ch = it * 256 + tid;
    int i = ch >> 6, c = ch & 63;
    float4 v = *(const float4*)(Of + i * 256 + c * 4);
    *(float4*)(out_h + (size_t)(n0 + i) * HH + c * 4) = v;
  }
}

// ---------------- launch ----------------
extern "C" void kernel_launch(void* const* d_in, const int* in_sizes, int n_in,
                              void* d_out, int out_size, void* d_ws, size_t ws_size,
                              hipStream_t stream) {
  const float* h = (const float*)d_in[0];
  const float* pos = (const float*)d_in[1];
  const float* rb_w1 = (const float*)d_in[2];
  const float* rb_b1 = (const float*)d_in[3];
  const float* rb_w2 = (const float*)d_in[4];
  const float* rb_b2 = (const float*)d_in[5];
  const float* en_w1 = (const float*)d_in[6];
  const float* en_b1 = (const float*)d_in[7];
  const float* en_w2 = (const float*)d_in[8];
  const float* en_b2 = (const float*)d_in[9];
  const float* en_g = (const float*)d_in[10];
  const float* en_bt = (const float*)d_in[11];
  const float* nn_w1 = (const float*)d_in[12];
  const float* nn_b1 = (const float*)d_in[13];
  const float* nn_w2 = (const float*)d_in[14];
  const float* nn_b2 = (const float*)d_in[15];
  const float* nn_g = (const float*)d_in[16];
  const float* nn_bt = (const float*)d_in[17];
  const float* cn_w1 = (const float*)d_in[18];
  const float* cn_b1 = (const float*)d_in[19];
  const float* cn_w2 = (const float*)d_in[20];
  const float* cn_b2 = (const float*)d_in[21];
  const int* ei = (const int*)d_in[22];

  float* out_h = (float*)d_out;
  float* out_pos = out_h + (size_t)NN * HH;

  // workspace bump allocator (256B aligned)
  char* p = (char*)d_ws;
  auto alloc = [&p](size_t bytes) {
    char* q = p;
    p += (bytes + 255) & ~(size_t)255;
    return q;
  };
  __hip_bfloat16* hb = (__hip_bfloat16*)alloc((size_t)NN * HH * 2);
  __hip_bfloat16* W1S = (__hip_bfloat16*)alloc((size_t)17 * HH * 40 * 2);
  __hip_bfloat16* W2S = (__hip_bfloat16*)alloc((size_t)8 * HH * 40 * 2);
  __hip_bfloat16* NW1S = (__hip_bfloat16*)alloc((size_t)16 * HH * 40 * 2);
  __hip_bfloat16* NW2S = (__hip_bfloat16*)alloc((size_t)8 * HH * 40 * 2);
  __hip_bfloat16* CW1S = (__hip_bfloat16*)alloc((size_t)8 * 128 * 40 * 2);
  __hip_bfloat16* radial = (__hip_bfloat16*)alloc((size_t)EE * RR * 2);
  __hip_bfloat16* emsg = (__hip_bfloat16*)alloc((size_t)EE * HH * 2);
  float* nmsg = (float*)alloc((size_t)NN * HH * 4);
  int* counts = (int*)alloc((size_t)NN * 4);
  int* offs = (int*)alloc((size_t)(NN + 1) * 4);
  int* cursor = (int*)alloc((size_t)NN * 4);
  int* elist = (int*)alloc((size_t)EE * 4);

  hipMemsetAsync(out_pos, 0, (size_t)NN * 3 * sizeof(float), stream);
  hipMemsetAsync(counts, 0, (size_t)NN * sizeof(int), stream);

  conv_h_kernel<<<(NN * HH / 4 + 255) / 256, 256, 0, stream>>>(h, hb, NN * HH / 4);
  slice_w_kernel<<<(544 * 256) / 256, 256, 0, stream>>>(en_w1, W1S, 544, 256);
  slice_w_kernel<<<(256 * 256) / 256, 256, 0, stream>>>(en_w2, W2S, 256, 256);
  slice_w_kernel<<<(512 * 256) / 256, 256, 0, stream>>>(nn_w1, NW1S, 512, 256);
  slice_w_kernel<<<(256 * 256) / 256, 256, 0, stream>>>(nn_w2, NW2S, 256, 256);
  slice_w_kernel<<<(256 * 128) / 256, 256, 0, stream>>>(cn_w1, CW1S, 256, 128);
  radial_kernel<<<EE / 256, 256, 0, stream>>>(ei, pos, rb_w1, rb_b1, rb_w2, rb_b2, radial);
  count_kernel<<<EE / 256, 256, 0, stream>>>(ei, counts);
  scan_kernel<<<1, 1024, 0, stream>>>(counts, offs, cursor);
  scatter_kernel<<<EE / 256, 256, 0, stream>>>(ei, cursor, elist);
  edge_kernel<<<EE / 64, 256, 0, stream>>>(hb, ei, pos, W1S, en_b1, W2S, en_b2, en_g, en_bt,
                                           CW1S, cn_b1, cn_w2, cn_b2, radial, emsg, out_pos);
  nodemsg_kernel<<<NN / 4, 256, 0, stream>>>(offs, elist, emsg, nmsg);
  node_kernel<<<NN / 64, 256, 0, stream>>>(hb, nmsg, NW1S, nn_b1, NW2S, nn_b2, nn_g, nn_bt,
                                           out_h);
}

// Round 2
// 526.055 us; speedup vs baseline: 1.6623x; 1.6623x over previous
//
#include <hip/hip_runtime.h>
#include <hip/hip_bf16.h>

// ---------------------------------------------------------------------------
// EGNN layer, v2: algebraic GEMM1 split + B-direct MFMA loops.
//   P = h @ [W1a|W1b]  (per-node precompute, [N,512] bf16)
//   edge: hidden = silu(P1[row]+P2[col] + s@RW + b1')  ; s = silu(dist*rbw1+rbb1)
//         msg    = LN(hidden @ W2 + b2)
//         coordw = tanh(dot(silu(msg @ CW1 + cb1), cw2) + cb2)
//   node: h' = LN(silu([h|nmsg] @ NW1 + b1) @ NW2 + b2)
// All B operands pre-transposed to [n][K] bf16 so B-fragments are direct
// global 16B loads (L2-resident, no LDS staging, no k-loop barriers).
// ---------------------------------------------------------------------------

#define NN 16384
#define EE 262144
#define HH 256
#define RR 32

typedef __bf16 bf16x8 __attribute__((ext_vector_type(8)));
typedef float f32x4 __attribute__((ext_vector_type(4)));

__device__ __forceinline__ float silu_f(float x) { return x / (1.0f + __expf(-x)); }

// ---------------- prep ----------------
__global__ __launch_bounds__(256) void conv_h_kernel(const float* __restrict__ src,
                                                     __hip_bfloat16* __restrict__ dst,
                                                     int n4) {
  int i = blockIdx.x * 256 + threadIdx.x;
  if (i >= n4) return;
  float4 v = ((const float4*)src)[i];
  __hip_bfloat16* d = dst + (size_t)i * 4;
  d[0] = __float2bfloat16(v.x);
  d[1] = __float2bfloat16(v.y);
  d[2] = __float2bfloat16(v.z);
  d[3] = __float2bfloat16(v.w);
}

// in [K][Nc] f32 -> out[c*K + k] bf16  (n-major, k-contiguous)
__global__ __launch_bounds__(256) void tr_kernel(const float* __restrict__ in,
                                                 __hip_bfloat16* __restrict__ out,
                                                 int K, int Nc) {
  int i = blockIdx.x * 256 + threadIdx.x;
  if (i >= K * Nc) return;
  int k = i / Nc, c = i - k * Nc;
  out[(size_t)c * K + k] = __float2bfloat16(in[i]);
}

// RWT[c][i] = sum_j rb_w2[i][j] * en_w1[512+j][c]   ([256][32] bf16)
__global__ __launch_bounds__(256) void rwt_kernel(const float* __restrict__ rb_w2,
                                                  const float* __restrict__ en_w1,
                                                  __hip_bfloat16* __restrict__ RWT) {
  int t = blockIdx.x * 256 + threadIdx.x;
  if (t >= 256 * 32) return;
  int c = t >> 5, i = t & 31;
  float s = 0.f;
#pragma unroll
  for (int j = 0; j < 32; ++j) s += rb_w2[i * 32 + j] * en_w1[(512 + j) * 256 + c];
  RWT[c * 32 + i] = __float2bfloat16(s);
}

// b1p[c] = en_b1[c] + sum_j rb_b2[j] * en_w1[512+j][c]
__global__ __launch_bounds__(256) void b1p_kernel(const float* __restrict__ en_b1,
                                                  const float* __restrict__ rb_b2,
                                                  const float* __restrict__ en_w1,
                                                  float* __restrict__ b1p) {
  int c = blockIdx.x * 256 + threadIdx.x;
  if (c >= 256) return;
  float s = en_b1[c];
#pragma unroll
  for (int j = 0; j < 32; ++j) s += rb_b2[j] * en_w1[(512 + j) * 256 + c];
  b1p[c] = s;
}

// ---------------- CSR build (col) ----------------
__global__ __launch_bounds__(256) void count_kernel(const int* __restrict__ ei,
                                                    int* __restrict__ counts) {
  int e = blockIdx.x * 256 + threadIdx.x;
  if (e >= EE) return;
  atomicAdd(&counts[ei[EE + e]], 1);
}

__global__ __launch_bounds__(1024) void scan_kernel(const int* __restrict__ counts,
                                                    int* __restrict__ offs,
                                                    int* __restrict__ cursor) {
  __shared__ int buf[1024];
  __shared__ int carry;
  int tid = threadIdx.x;
  if (tid == 0) carry = 0;
  __syncthreads();
  for (int base = 0; base < NN; base += 1024) {
    int v = counts[base + tid];
    buf[tid] = v;
    __syncthreads();
    for (int s = 1; s < 1024; s <<= 1) {
      int x = (tid >= s) ? buf[tid - s] : 0;
      __syncthreads();
      buf[tid] += x;
      __syncthreads();
    }
    int incl = buf[tid];
    int c = carry;
    __syncthreads();
    offs[base + tid] = c + incl - v;
    cursor[base + tid] = c + incl - v;
    if (tid == 1023) carry = c + incl;
    __syncthreads();
  }
  if (tid == 0) offs[NN] = carry;
}

__global__ __launch_bounds__(256) void scatter_kernel(const int* __restrict__ ei,
                                                      int* __restrict__ cursor,
                                                      int* __restrict__ elist) {
  int e = blockIdx.x * 256 + threadIdx.x;
  if (e >= EE) return;
  int c = ei[EE + e];
  int p = atomicAdd(&cursor[c], 1);
  elist[p] = e;
}

// ---------------- P = h @ [W1a|W1b] : [N,512] bf16 ----------------
// 64 rows/block, 8 waves; wave w -> cols [64w,64w+64); A,B direct global.
__global__ __launch_bounds__(512) void pgemm_kernel(const __hip_bfloat16* __restrict__ A,
                                                    const __hip_bfloat16* __restrict__ BT,
                                                    __hip_bfloat16* __restrict__ out) {
  const int tid = threadIdx.x, w = tid >> 6, l = tid & 63, r = l & 15, g = l >> 4;
  const int n0 = blockIdx.x * 64;
  f32x4 acc[4][4];
#pragma unroll
  for (int a = 0; a < 4; ++a)
#pragma unroll
    for (int b = 0; b < 4; ++b) acc[a][b] = (f32x4){0.f, 0.f, 0.f, 0.f};
  for (int ks = 0; ks < 8; ++ks) {
    bf16x8 af[4], bfr[4];
#pragma unroll
    for (int fm = 0; fm < 4; ++fm)
      af[fm] = *(const bf16x8*)(A + (size_t)(n0 + fm * 16 + r) * 256 + ks * 32 + g * 8);
#pragma unroll
    for (int fn = 0; fn < 4; ++fn)
      bfr[fn] = *(const bf16x8*)(BT + (size_t)(w * 64 + fn * 16 + r) * 256 + ks * 32 + g * 8);
#pragma unroll
    for (int fm = 0; fm < 4; ++fm)
#pragma unroll
      for (int fn = 0; fn < 4; ++fn)
        acc[fm][fn] =
            __builtin_amdgcn_mfma_f32_16x16x32_bf16(af[fm], bfr[fn], acc[fm][fn], 0, 0, 0);
  }
#pragma unroll
  for (int fm = 0; fm < 4; ++fm)
#pragma unroll
    for (int fn = 0; fn < 4; ++fn) {
      int col = w * 64 + fn * 16 + r;
#pragma unroll
      for (int q = 0; q < 4; ++q) {
        int row = n0 + fm * 16 + g * 4 + q;
        out[(size_t)row * 512 + col] = __float2bfloat16(acc[fm][fn][q]);
      }
    }
}

// ---------------- fused edge kernel ----------------
// 64 edges/block, 512 threads (8 waves). Wave w -> output cols [32w,32w+32).
__global__ __launch_bounds__(512, 4) void edge_kernel(
    const __hip_bfloat16* __restrict__ Pb, const int* __restrict__ ei,
    const float* __restrict__ pos, const float* __restrict__ rb_w1,
    const float* __restrict__ rb_b1, const __hip_bfloat16* __restrict__ RWT,
    const float* __restrict__ b1p, const __hip_bfloat16* __restrict__ W2T,
    const float* __restrict__ en_b2, const float* __restrict__ en_g,
    const float* __restrict__ en_bt, const __hip_bfloat16* __restrict__ CW1T,
    const float* __restrict__ cn_b1, const float* __restrict__ cn_w2,
    const float* __restrict__ cn_b2, __hip_bfloat16* __restrict__ emsg,
    float* __restrict__ pos_out) {
  __shared__ __align__(16) __hip_bfloat16 A2[64 * 264];  // 33 KB tile (Psum->hidden->msg)
  __shared__ float distb[64];
  __shared__ float relb[64][3];
  __shared__ int srow[64], scol[64];
  __shared__ float wc1[32], bc1[32];
  __shared__ float red[8][64], redsq[8][64], red2[8][64];
  __shared__ float mv[64][2];
  __shared__ float gb[HH], btb[HH], cb1b[128], cw2b[128];

  const int tid = threadIdx.x, w = tid >> 6, l = tid & 63, r = l & 15, g = l >> 4;
  const int e0 = blockIdx.x * 64;

  if (tid < 256) {
    gb[tid] = en_g[tid];
    btb[tid] = en_bt[tid];
  }
  if (tid < 128) {
    cb1b[tid] = cn_b1[tid];
    cw2b[tid] = cn_w2[tid];
  }
  if (tid < 32) {
    wc1[tid] = rb_w1[tid];
    bc1[tid] = rb_b1[tid];
  }
  if (tid < 64) {
    int e = e0 + tid;
    int rr = ei[e], cc = ei[EE + e];
    srow[tid] = rr;
    scol[tid] = cc;
    float dx = pos[cc * 3 + 0] - pos[rr * 3 + 0];
    float dy = pos[cc * 3 + 1] - pos[rr * 3 + 1];
    float dz = pos[cc * 3 + 2] - pos[rr * 3 + 2];
    relb[tid][0] = dx;
    relb[tid][1] = dy;
    relb[tid][2] = dz;
    float ex = dx + 1e-8f, ey = dy + 1e-8f, ez = dz + 1e-8f;
    distb[tid] = sqrtf(ex * ex + ey * ey + ez * ez);
  }
  __syncthreads();

  // stage Psum = P1[srow] + P2[scol] into A2 (bf16), coalesced 16B chunks
#pragma unroll
  for (int it = 0; it < 4; ++it) {
    int ch = it * 512 + tid;  // 2048 chunks
    int i = ch >> 5, c = ch & 31;
    bf16x8 p1 = *(const bf16x8*)(Pb + (size_t)srow[i] * 512 + c * 8);
    bf16x8 p2 = *(const bf16x8*)(Pb + (size_t)scol[i] * 512 + 256 + c * 8);
    bf16x8 o;
#pragma unroll
    for (int j = 0; j < 8; ++j) o[j] = (__bf16)((float)p1[j] + (float)p2[j]);
    *(bf16x8*)(A2 + i * 264 + c * 8) = o;
  }

  // radial term: acc = s @ RW  (single K=32 step), s computed in-register
  f32x4 acc[4][2];
  {
    bf16x8 sf[4], bfr[2];
#pragma unroll
    for (int fm = 0; fm < 4; ++fm) {
      float d = distb[fm * 16 + r];
      bf16x8 v;
#pragma unroll
      for (int j = 0; j < 8; ++j) {
        float x = d * wc1[g * 8 + j] + bc1[g * 8 + j];
        v[j] = (__bf16)silu_f(x);
      }
      sf[fm] = v;
    }
#pragma unroll
    for (int fn = 0; fn < 2; ++fn)
      bfr[fn] = *(const bf16x8*)(RWT + (size_t)(w * 32 + fn * 16 + r) * 32 + g * 8);
#pragma unroll
    for (int fm = 0; fm < 4; ++fm)
#pragma unroll
      for (int fn = 0; fn < 2; ++fn)
        acc[fm][fn] = __builtin_amdgcn_mfma_f32_16x16x32_bf16(
            sf[fm], bfr[fn], (f32x4){0.f, 0.f, 0.f, 0.f}, 0, 0, 0);
  }
  __syncthreads();  // Psum visible

  // hidden = silu(acc + Psum + b1')  -> A2 in-place (1:1 lane ownership)
#pragma unroll
  for (int fn = 0; fn < 2; ++fn) {
    int col = w * 32 + fn * 16 + r;
    float bp = b1p[col];
#pragma unroll
    for (int fm = 0; fm < 4; ++fm)
#pragma unroll
      for (int q = 0; q < 4; ++q) {
        int row = fm * 16 + g * 4 + q;
        float ps = __bfloat162float(A2[row * 264 + col]);
        A2[row * 264 + col] = __float2bfloat16(silu_f(acc[fm][fn][q] + ps + bp));
      }
  }
  __syncthreads();

  // ---- GEMM2: K=256, A from LDS, B direct global, no barriers ----
#pragma unroll
  for (int a = 0; a < 4; ++a)
#pragma unroll
    for (int b = 0; b < 2; ++b) acc[a][b] = (f32x4){0.f, 0.f, 0.f, 0.f};
  for (int ks = 0; ks < 8; ++ks) {
    bf16x8 af[4], bfr[2];
#pragma unroll
    for (int fm = 0; fm < 4; ++fm)
      af[fm] = *(const bf16x8*)(A2 + (fm * 16 + r) * 264 + ks * 32 + g * 8);
#pragma unroll
    for (int fn = 0; fn < 2; ++fn)
      bfr[fn] = *(const bf16x8*)(W2T + (size_t)(w * 32 + fn * 16 + r) * 256 + ks * 32 + g * 8);
#pragma unroll
    for (int fm = 0; fm < 4; ++fm)
#pragma unroll
      for (int fn = 0; fn < 2; ++fn)
        acc[fm][fn] =
            __builtin_amdgcn_mfma_f32_16x16x32_bf16(af[fm], bfr[fn], acc[fm][fn], 0, 0, 0);
  }
#pragma unroll
  for (int fn = 0; fn < 2; ++fn) {
    float b2 = en_b2[w * 32 + fn * 16 + r];
#pragma unroll
    for (int fm = 0; fm < 4; ++fm)
#pragma unroll
      for (int q = 0; q < 4; ++q) acc[fm][fn][q] += b2;
  }

  // LayerNorm: per-row stats (each wave covers all 64 rows x its 32 cols)
#pragma unroll
  for (int fm = 0; fm < 4; ++fm)
#pragma unroll
    for (int q = 0; q < 4; ++q) {
      float s = acc[fm][0][q] + acc[fm][1][q];
      float sq = acc[fm][0][q] * acc[fm][0][q] + acc[fm][1][q] * acc[fm][1][q];
#pragma unroll
      for (int m = 1; m < 16; m <<= 1) {
        s += __shfl_xor(s, m, 64);
        sq += __shfl_xor(sq, m, 64);
      }
      if (r == 0) {
        red[w][fm * 16 + g * 4 + q] = s;
        redsq[w][fm * 16 + g * 4 + q] = sq;
      }
    }
  __syncthreads();
  if (tid < 64) {
    float s = 0.f, sq = 0.f;
#pragma unroll
    for (int k = 0; k < 8; ++k) {
      s += red[k][tid];
      sq += redsq[k][tid];
    }
    float mean = s * (1.0f / HH);
    float var = sq * (1.0f / HH) - mean * mean;
    mv[tid][0] = mean;
    mv[tid][1] = rsqrtf(var + 1e-5f);
  }
  __syncthreads();
#pragma unroll
  for (int fn = 0; fn < 2; ++fn) {
    int col = w * 32 + fn * 16 + r;
    float gg = gb[col], bb = btb[col];
#pragma unroll
    for (int fm = 0; fm < 4; ++fm)
#pragma unroll
      for (int q = 0; q < 4; ++q) {
        int row = fm * 16 + g * 4 + q;
        A2[row * 264 + col] =
            __float2bfloat16((acc[fm][fn][q] - mv[row][0]) * mv[row][1] * gg + bb);
      }
  }
  __syncthreads();

  // store edge_msg (coalesced 16B)
#pragma unroll
  for (int it = 0; it < 4; ++it) {
    int ch = it * 512 + tid;
    int i = ch >> 5, c = ch & 31;
    *(float4*)(emsg + (size_t)(e0 + i) * HH + c * 8) = *(const float4*)(A2 + i * 264 + c * 8);
  }

  // ---- coord head: msg @ CW1 (wave -> 16 cols), silu*w2, row-reduce, tanh ----
  f32x4 c2[4];
#pragma unroll
  for (int a = 0; a < 4; ++a) c2[a] = (f32x4){0.f, 0.f, 0.f, 0.f};
  for (int ks = 0; ks < 8; ++ks) {
    bf16x8 af[4];
#pragma unroll
    for (int fm = 0; fm < 4; ++fm)
      af[fm] = *(const bf16x8*)(A2 + (fm * 16 + r) * 264 + ks * 32 + g * 8);
    bf16x8 bfr = *(const bf16x8*)(CW1T + (size_t)(w * 16 + r) * 256 + ks * 32 + g * 8);
#pragma unroll
    for (int fm = 0; fm < 4; ++fm)
      c2[fm] = __builtin_amdgcn_mfma_f32_16x16x32_bf16(af[fm], bfr, c2[fm], 0, 0, 0);
  }
  {
    int ccol = w * 16 + r;
    float cb = cb1b[ccol], cw = cw2b[ccol];
#pragma unroll
    for (int fm = 0; fm < 4; ++fm)
#pragma unroll
      for (int q = 0; q < 4; ++q) {
        float v = silu_f(c2[fm][q] + cb) * cw;
#pragma unroll
        for (int m = 1; m < 16; m <<= 1) v += __shfl_xor(v, m, 64);
        if (r == 0) red2[w][fm * 16 + g * 4 + q] = v;
      }
  }
  __syncthreads();
  if (tid < 64) {
    float s = cn_b2[0];
#pragma unroll
    for (int k = 0; k < 8; ++k) s += red2[k][tid];
    float wgt = tanhf(s);
    float ax = relb[tid][0], ay = relb[tid][1], az = relb[tid][2];
    int rr = srow[tid], cc = scol[tid];
    atomicAdd(&pos_out[rr * 3 + 0], -wgt * ax);
    atomicAdd(&pos_out[rr * 3 + 1], -wgt * ay);
    atomicAdd(&pos_out[rr * 3 + 2], -wgt * az);
    atomicAdd(&pos_out[cc * 3 + 0], wgt * ax);
    atomicAdd(&pos_out[cc * 3 + 1], wgt * ay);
    atomicAdd(&pos_out[cc * 3 + 2], wgt * az);
  }
}

// ---------------- node_msg = segment_sum(edge_msg, col) via CSR, bf16 out ----------------
__global__ __launch_bounds__(256) void nodemsg_kernel(const int* __restrict__ offs,
                                                      const int* __restrict__ elist,
                                                      const __hip_bfloat16* __restrict__ emsg,
                                                      __hip_bfloat16* __restrict__ nmsgb) {
  int wid = threadIdx.x >> 6, l = threadIdx.x & 63;
  int n = blockIdx.x * 4 + wid;
  float a0 = 0.f, a1 = 0.f, a2 = 0.f, a3 = 0.f;
  int b = offs[n], e2 = offs[n + 1];
  for (int idx = b; idx < e2; ++idx) {
    int e = elist[idx];
    const __hip_bfloat16* row = emsg + (size_t)e * HH;
    a0 += __bfloat162float(row[l]);
    a1 += __bfloat162float(row[l + 64]);
    a2 += __bfloat162float(row[l + 128]);
    a3 += __bfloat162float(row[l + 192]);
  }
  __hip_bfloat16* out = nmsgb + (size_t)n * HH;
  out[l] = __float2bfloat16(a0);
  out[l + 64] = __float2bfloat16(a1);
  out[l + 128] = __float2bfloat16(a2);
  out[l + 192] = __float2bfloat16(a3);
}

// ---------------- fused node kernel: 32 nodes/block, 8 waves ----------------
__global__ __launch_bounds__(512, 4) void node_kernel(
    const __hip_bfloat16* __restrict__ hb, const __hip_bfloat16* __restrict__ nmsgb,
    const __hip_bfloat16* __restrict__ NW1T, const float* __restrict__ nn_b1,
    const __hip_bfloat16* __restrict__ NW2T, const float* __restrict__ nn_b2,
    const float* __restrict__ nn_g, const float* __restrict__ nn_bt,
    float* __restrict__ out_h) {
  __shared__ __align__(16) __hip_bfloat16 A2[32 * 264];
  __shared__ float red[8][32], redsq[8][32];
  __shared__ float mv[32][2];
  __shared__ float gb[HH], btb[HH];
  const int tid = threadIdx.x, w = tid >> 6, l = tid & 63, r = l & 15, g = l >> 4;
  const int n0 = blockIdx.x * 32;
  if (tid < 256) {
    gb[tid] = nn_g[tid];
    btb[tid] = nn_bt[tid];
  }

  f32x4 acc[2][2];
#pragma unroll
  for (int a = 0; a < 2; ++a)
#pragma unroll
    for (int b = 0; b < 2; ++b) acc[a][b] = (f32x4){0.f, 0.f, 0.f, 0.f};
  // GEMM1: K=512 (h | nmsg), A and B direct global
  for (int ks = 0; ks < 8; ++ks) {
    bf16x8 af[2], bfr[2];
#pragma unroll
    for (int fm = 0; fm < 2; ++fm)
      af[fm] = *(const bf16x8*)(hb + (size_t)(n0 + fm * 16 + r) * 256 + ks * 32 + g * 8);
#pragma unroll
    for (int fn = 0; fn < 2; ++fn)
      bfr[fn] = *(const bf16x8*)(NW1T + (size_t)(w * 32 + fn * 16 + r) * 512 + ks * 32 + g * 8);
#pragma unroll
    for (int fm = 0; fm < 2; ++fm)
#pragma unroll
      for (int fn = 0; fn < 2; ++fn)
        acc[fm][fn] =
            __builtin_amdgcn_mfma_f32_16x16x32_bf16(af[fm], bfr[fn], acc[fm][fn], 0, 0, 0);
  }
  for (int ks = 0; ks < 8; ++ks) {
    bf16x8 af[2], bfr[2];
#pragma unroll
    for (int fm = 0; fm < 2; ++fm)
      af[fm] = *(const bf16x8*)(nmsgb + (size_t)(n0 + fm * 16 + r) * 256 + ks * 32 + g * 8);
#pragma unroll
    for (int fn = 0; fn < 2; ++fn)
      bfr[fn] = *(const bf16x8*)(NW1T + (size_t)(w * 32 + fn * 16 + r) * 512 + 256 + ks * 32 + g * 8);
#pragma unroll
    for (int fm = 0; fm < 2; ++fm)
#pragma unroll
      for (int fn = 0; fn < 2; ++fn)
        acc[fm][fn] =
            __builtin_amdgcn_mfma_f32_16x16x32_bf16(af[fm], bfr[fn], acc[fm][fn], 0, 0, 0);
  }
  __syncthreads();  // gb/btb ready; also orders A2 writes below
#pragma unroll
  for (int fn = 0; fn < 2; ++fn) {
    int col = w * 32 + fn * 16 + r;
    float b1 = nn_b1[col];
#pragma unroll
    for (int fm = 0; fm < 2; ++fm)
#pragma unroll
      for (int q = 0; q < 4; ++q) {
        int row = fm * 16 + g * 4 + q;
        A2[row * 264 + col] = __float2bfloat16(silu_f(acc[fm][fn][q] + b1));
      }
  }
  __syncthreads();

  // GEMM2: K=256
#pragma unroll
  for (int a = 0; a < 2; ++a)
#pragma unroll
    for (int b = 0; b < 2; ++b) acc[a][b] = (f32x4){0.f, 0.f, 0.f, 0.f};
  for (int ks = 0; ks < 8; ++ks) {
    bf16x8 af[2], bfr[2];
#pragma unroll
    for (int fm = 0; fm < 2; ++fm)
      af[fm] = *(const bf16x8*)(A2 + (fm * 16 + r) * 264 + ks * 32 + g * 8);
#pragma unroll
    for (int fn = 0; fn < 2; ++fn)
      bfr[fn] = *(const bf16x8*)(NW2T + (size_t)(w * 32 + fn * 16 + r) * 256 + ks * 32 + g * 8);
#pragma unroll
    for (int fm = 0; fm < 2; ++fm)
#pragma unroll
      for (int fn = 0; fn < 2; ++fn)
        acc[fm][fn] =
            __builtin_amdgcn_mfma_f32_16x16x32_bf16(af[fm], bfr[fn], acc[fm][fn], 0, 0, 0);
  }
#pragma unroll
  for (int fn = 0; fn < 2; ++fn) {
    float b2 = nn_b2[w * 32 + fn * 16 + r];
#pragma unroll
    for (int fm = 0; fm < 2; ++fm)
#pragma unroll
      for (int q = 0; q < 4; ++q) acc[fm][fn][q] += b2;
  }
#pragma unroll
  for (int fm = 0; fm < 2; ++fm)
#pragma unroll
    for (int q = 0; q < 4; ++q) {
      float s = acc[fm][0][q] + acc[fm][1][q];
      float sq = acc[fm][0][q] * acc[fm][0][q] + acc[fm][1][q] * acc[fm][1][q];
#pragma unroll
      for (int m = 1; m < 16; m <<= 1) {
        s += __shfl_xor(s, m, 64);
        sq += __shfl_xor(sq, m, 64);
      }
      if (r == 0) {
        red[w][fm * 16 + g * 4 + q] = s;
        redsq[w][fm * 16 + g * 4 + q] = sq;
      }
    }
  __syncthreads();
  if (tid < 32) {
    float s = 0.f, sq = 0.f;
#pragma unroll
    for (int k = 0; k < 8; ++k) {
      s += red[k][tid];
      sq += redsq[k][tid];
    }
    float mean = s * (1.0f / HH);
    float var = sq * (1.0f / HH) - mean * mean;
    mv[tid][0] = mean;
    mv[tid][1] = rsqrtf(var + 1e-5f);
  }
  __syncthreads();
#pragma unroll
  for (int fn = 0; fn < 2; ++fn) {
    int col = w * 32 + fn * 16 + r;
    float gg = gb[col], bb = btb[col];
#pragma unroll
    for (int fm = 0; fm < 2; ++fm)
#pragma unroll
      for (int q = 0; q < 4; ++q) {
        int row = fm * 16 + g * 4 + q;
        out_h[(size_t)(n0 + row) * HH + col] =
            (acc[fm][fn][q] - mv[row][0]) * mv[row][1] * gg + bb;
      }
  }
}

// ---------------- launch ----------------
extern "C" void kernel_launch(void* const* d_in, const int* in_sizes, int n_in,
                              void* d_out, int out_size, void* d_ws, size_t ws_size,
                              hipStream_t stream) {
  const float* h = (const float*)d_in[0];
  const float* pos = (const float*)d_in[1];
  const float* rb_w1 = (const float*)d_in[2];
  const float* rb_b1 = (const float*)d_in[3];
  const float* rb_w2 = (const float*)d_in[4];
  const float* rb_b2 = (const float*)d_in[5];
  const float* en_w1 = (const float*)d_in[6];
  const float* en_b1 = (const float*)d_in[7];
  const float* en_w2 = (const float*)d_in[8];
  const float* en_b2 = (const float*)d_in[9];
  const float* en_g = (const float*)d_in[10];
  const float* en_bt = (const float*)d_in[11];
  const float* nn_w1 = (const float*)d_in[12];
  const float* nn_b1 = (const float*)d_in[13];
  const float* nn_w2 = (const float*)d_in[14];
  const float* nn_b2 = (const float*)d_in[15];
  const float* nn_g = (const float*)d_in[16];
  const float* nn_bt = (const float*)d_in[17];
  const float* cn_w1 = (const float*)d_in[18];
  const float* cn_b1 = (const float*)d_in[19];
  const float* cn_w2 = (const float*)d_in[20];
  const float* cn_b2 = (const float*)d_in[21];
  const int* ei = (const int*)d_in[22];

  float* out_h = (float*)d_out;
  float* out_pos = out_h + (size_t)NN * HH;

  char* p = (char*)d_ws;
  auto alloc = [&p](size_t bytes) {
    char* q = p;
    p += (bytes + 255) & ~(size_t)255;
    return q;
  };
  __hip_bfloat16* hb = (__hip_bfloat16*)alloc((size_t)NN * HH * 2);
  __hip_bfloat16* Pb = (__hip_bfloat16*)alloc((size_t)NN * 512 * 2);
  __hip_bfloat16* W1abT = (__hip_bfloat16*)alloc((size_t)512 * 256 * 2);
  __hip_bfloat16* W2T = (__hip_bfloat16*)alloc((size_t)256 * 256 * 2);
  __hip_bfloat16* NW1T = (__hip_bfloat16*)alloc((size_t)256 * 512 * 2);
  __hip_bfloat16* NW2T = (__hip_bfloat16*)alloc((size_t)256 * 256 * 2);
  __hip_bfloat16* CW1T = (__hip_bfloat16*)alloc((size_t)128 * 256 * 2);
  __hip_bfloat16* RWT = (__hip_bfloat16*)alloc((size_t)256 * 32 * 2);
  float* b1p = (float*)alloc((size_t)256 * 4);
  __hip_bfloat16* emsg = (__hip_bfloat16*)alloc((size_t)EE * HH * 2);
  __hip_bfloat16* nmsgb = (__hip_bfloat16*)alloc((size_t)NN * HH * 2);
  int* counts = (int*)alloc((size_t)NN * 4);
  int* offs = (int*)alloc((size_t)(NN + 1) * 4);
  int* cursor = (int*)alloc((size_t)NN * 4);
  int* elist = (int*)alloc((size_t)EE * 4);

  hipMemsetAsync(out_pos, 0, (size_t)NN * 3 * sizeof(float), stream);
  hipMemsetAsync(counts, 0, (size_t)NN * sizeof(int), stream);

  conv_h_kernel<<<(NN * HH / 4 + 255) / 256, 256, 0, stream>>>(h, hb, NN * HH / 4);
  tr_kernel<<<(256 * 256) / 256, 256, 0, stream>>>(en_w2, W2T, 256, 256);
  tr_kernel<<<(512 * 256) / 256, 256, 0, stream>>>(nn_w1, NW1T, 512, 256);
  tr_kernel<<<(256 * 256) / 256, 256, 0, stream>>>(nn_w2, NW2T, 256, 256);
  tr_kernel<<<(256 * 128) / 256, 256, 0, stream>>>(cn_w1, CW1T, 256, 128);
  tr_kernel<<<(256 * 256) / 256, 256, 0, stream>>>(en_w1, W1abT, 256, 256);
  tr_kernel<<<(256 * 256) / 256, 256, 0, stream>>>(en_w1 + 256 * 256, W1abT + 256 * 256, 256,
                                                   256);
  rwt_kernel<<<(256 * 32) / 256, 256, 0, stream>>>(rb_w2, en_w1, RWT);
  b1p_kernel<<<1, 256, 0, stream>>>(en_b1, rb_b2, en_w1, b1p);
  count_kernel<<<EE / 256, 256, 0, stream>>>(ei, counts);
  scan_kernel<<<1, 1024, 0, stream>>>(counts, offs, cursor);
  scatter_kernel<<<EE / 256, 256, 0, stream>>>(ei, cursor, elist);
  pgemm_kernel<<<NN / 64, 512, 0, stream>>>(hb, W1abT, Pb);
  edge_kernel<<<EE / 64, 512, 0, stream>>>(Pb, ei, pos, rb_w1, rb_b1, RWT, b1p, W2T, en_b2,
                                           en_g, en_bt, CW1T, cn_b1, cn_w2, cn_b2, emsg,
                                           out_pos);
  nodemsg_kernel<<<NN / 4, 256, 0, stream>>>(offs, elist, emsg, nmsgb);
  node_kernel<<<NN / 32, 512, 0, stream>>>(hb, nmsgb, NW1T, nn_b1, NW2T, nn_b2, nn_g, nn_bt,
                                           out_h);
}

// Round 3
// 521.417 us; speedup vs baseline: 1.6771x; 1.0089x over previous
//
#include <hip/hip_runtime.h>
#include <hip/hip_bf16.h>

// ---------------------------------------------------------------------------
// EGNN layer, v3: transposed radial+Psum front-end (lane-local gather, no
// staging round-trip), hierarchical scan, vectorized nodemsg.
//   P = h @ [W1a|W1b]  (per-node precompute, [N,512] bf16)
//   edge: hidden = silu(P1[row]+P2[col] + s@RW + b1')  via D[c][e] MFMA swap
//         msg    = LN(hidden @ W2 + b2)
//         coordw = tanh(dot(silu(msg @ CW1 + cb1), cw2) + cb2)
//   node: h' = LN(silu([h|nmsg] @ NW1 + b1) @ NW2 + b2)
// ---------------------------------------------------------------------------

#define NN 16384
#define EE 262144
#define HH 256
#define RR 32

typedef __bf16 bf16x8 __attribute__((ext_vector_type(8)));
typedef float f32x4 __attribute__((ext_vector_type(4)));

__device__ __forceinline__ float silu_f(float x) { return x / (1.0f + __expf(-x)); }

__device__ __forceinline__ unsigned short bf_bits(float x) {
  union { __hip_bfloat16 b; unsigned short u; } v;
  v.b = __float2bfloat16(x);
  return v.u;
}
__device__ __forceinline__ float ubf(unsigned short u) {
  return __uint_as_float(((unsigned)u) << 16);
}

// ---------------- prep ----------------
__global__ __launch_bounds__(256) void conv_h_kernel(const float* __restrict__ src,
                                                     __hip_bfloat16* __restrict__ dst,
                                                     int n4) {
  int i = blockIdx.x * 256 + threadIdx.x;
  if (i >= n4) return;
  float4 v = ((const float4*)src)[i];
  __hip_bfloat16* d = dst + (size_t)i * 4;
  d[0] = __float2bfloat16(v.x);
  d[1] = __float2bfloat16(v.y);
  d[2] = __float2bfloat16(v.z);
  d[3] = __float2bfloat16(v.w);
}

// in [K][Nc] f32 -> out[c*K + k] bf16  (n-major, k-contiguous)
__global__ __launch_bounds__(256) void tr_kernel(const float* __restrict__ in,
                                                 __hip_bfloat16* __restrict__ out,
                                                 int K, int Nc) {
  int i = blockIdx.x * 256 + threadIdx.x;
  if (i >= K * Nc) return;
  int k = i / Nc, c = i - k * Nc;
  out[(size_t)c * K + k] = __float2bfloat16(in[i]);
}

// RWT[c][i] = sum_j rb_w2[i][j] * en_w1[512+j][c]   ([256][32] bf16)
__global__ __launch_bounds__(256) void rwt_kernel(const float* __restrict__ rb_w2,
                                                  const float* __restrict__ en_w1,
                                                  __hip_bfloat16* __restrict__ RWT) {
  int t = blockIdx.x * 256 + threadIdx.x;
  if (t >= 256 * 32) return;
  int c = t >> 5, i = t & 31;
  float s = 0.f;
#pragma unroll
  for (int j = 0; j < 32; ++j) s += rb_w2[i * 32 + j] * en_w1[(512 + j) * 256 + c];
  RWT[c * 32 + i] = __float2bfloat16(s);
}

// b1p[c] = en_b1[c] + sum_j rb_b2[j] * en_w1[512+j][c]
__global__ __launch_bounds__(256) void b1p_kernel(const float* __restrict__ en_b1,
                                                  const float* __restrict__ rb_b2,
                                                  const float* __restrict__ en_w1,
                                                  float* __restrict__ b1p) {
  int c = blockIdx.x * 256 + threadIdx.x;
  if (c >= 256) return;
  float s = en_b1[c];
#pragma unroll
  for (int j = 0; j < 32; ++j) s += rb_b2[j] * en_w1[(512 + j) * 256 + c];
  b1p[c] = s;
}

// ---------------- CSR build (col) ----------------
__global__ __launch_bounds__(256) void count_kernel(const int* __restrict__ ei,
                                                    int* __restrict__ counts) {
  int e = blockIdx.x * 256 + threadIdx.x;
  if (e >= EE) return;
  atomicAdd(&counts[ei[EE + e]], 1);
}

// hierarchical exclusive scan of counts[NN] (NN = 64 blocks x 256)
__global__ __launch_bounds__(256) void scanA_kernel(const int* __restrict__ counts,
                                                    int* __restrict__ bsum) {
  __shared__ int ws[4];
  int t = threadIdx.x;
  int v = counts[blockIdx.x * 256 + t];
#pragma unroll
  for (int m = 1; m < 64; m <<= 1) v += __shfl_xor(v, m, 64);
  if ((t & 63) == 0) ws[t >> 6] = v;
  __syncthreads();
  if (t == 0) bsum[blockIdx.x] = ws[0] + ws[1] + ws[2] + ws[3];
}

__global__ __launch_bounds__(64) void scanB_kernel(const int* __restrict__ bsum,
                                                   int* __restrict__ bbase,
                                                   int* __restrict__ offs) {
  int t = threadIdx.x;
  int v = bsum[t], x = v;
#pragma unroll
  for (int d = 1; d < 64; d <<= 1) {
    int y = __shfl_up(x, d, 64);
    if (t >= d) x += y;
  }
  bbase[t] = x - v;
  if (t == 63) offs[NN] = x;  // total == EE
}

__global__ __launch_bounds__(256) void scanC_kernel(const int* __restrict__ counts,
                                                    const int* __restrict__ bbase,
                                                    int* __restrict__ offs,
                                                    int* __restrict__ cursor) {
  __shared__ int wtot[4];
  int t = threadIdx.x, wv = t >> 6, ln = t & 63;
  int base = blockIdx.x * 256;
  int v = counts[base + t], x = v;
#pragma unroll
  for (int d = 1; d < 64; d <<= 1) {
    int y = __shfl_up(x, d, 64);
    if (ln >= d) x += y;
  }
  if (ln == 63) wtot[wv] = x;
  __syncthreads();
  int add = bbase[blockIdx.x];
  for (int k = 0; k < wv; ++k) add += wtot[k];
  int excl = add + x - v;
  offs[base + t] = excl;
  cursor[base + t] = excl;
}

__global__ __launch_bounds__(256) void scatter_kernel(const int* __restrict__ ei,
                                                      int* __restrict__ cursor,
                                                      int* __restrict__ elist) {
  int e = blockIdx.x * 256 + threadIdx.x;
  if (e >= EE) return;
  int c = ei[EE + e];
  int p = atomicAdd(&cursor[c], 1);
  elist[p] = e;
}

// ---------------- P = h @ [W1a|W1b] : [N,512] bf16 ----------------
__global__ __launch_bounds__(512) void pgemm_kernel(const __hip_bfloat16* __restrict__ A,
                                                    const __hip_bfloat16* __restrict__ BT,
                                                    __hip_bfloat16* __restrict__ out) {
  const int tid = threadIdx.x, w = tid >> 6, l = tid & 63, r = l & 15, g = l >> 4;
  const int n0 = blockIdx.x * 64;
  f32x4 acc[4][4];
#pragma unroll
  for (int a = 0; a < 4; ++a)
#pragma unroll
    for (int b = 0; b < 4; ++b) acc[a][b] = (f32x4){0.f, 0.f, 0.f, 0.f};
  for (int ks = 0; ks < 8; ++ks) {
    bf16x8 af[4], bfr[4];
#pragma unroll
    for (int fm = 0; fm < 4; ++fm)
      af[fm] = *(const bf16x8*)(A + (size_t)(n0 + fm * 16 + r) * 256 + ks * 32 + g * 8);
#pragma unroll
    for (int fn = 0; fn < 4; ++fn)
      bfr[fn] = *(const bf16x8*)(BT + (size_t)(w * 64 + fn * 16 + r) * 256 + ks * 32 + g * 8);
#pragma unroll
    for (int fm = 0; fm < 4; ++fm)
#pragma unroll
      for (int fn = 0; fn < 4; ++fn)
        acc[fm][fn] =
            __builtin_amdgcn_mfma_f32_16x16x32_bf16(af[fm], bfr[fn], acc[fm][fn], 0, 0, 0);
  }
#pragma unroll
  for (int fm = 0; fm < 4; ++fm)
#pragma unroll
    for (int fn = 0; fn < 4; ++fn) {
      int col = w * 64 + fn * 16 + r;
#pragma unroll
      for (int q = 0; q < 4; ++q) {
        int row = n0 + fm * 16 + g * 4 + q;
        out[(size_t)row * 512 + col] = __float2bfloat16(acc[fm][fn][q]);
      }
    }
}

// ---------------- fused edge kernel ----------------
// 64 edges/block, 512 threads (8 waves).
// Phase B (transposed): wave w -> eblk=w&3 (its 16 edges, e=eblk*16+r lane-fixed),
//   c-blocks (w>>2)*8+t. D[c][e] = mfma(RWT-rows, s-frag); hidden written as
//   lane-local 8B chunks. Then GEMM2/LN/coord use the standard orientation.
__global__ __launch_bounds__(512, 4) void edge_kernel(
    const __hip_bfloat16* __restrict__ Pb, const int* __restrict__ ei,
    const float* __restrict__ pos, const float* __restrict__ rb_w1,
    const float* __restrict__ rb_b1, const __hip_bfloat16* __restrict__ RWT,
    const float* __restrict__ b1p, const __hip_bfloat16* __restrict__ W2T,
    const float* __restrict__ en_b2, const float* __restrict__ en_g,
    const float* __restrict__ en_bt, const __hip_bfloat16* __restrict__ CW1T,
    const float* __restrict__ cn_b1, const float* __restrict__ cn_w2,
    const float* __restrict__ cn_b2, __hip_bfloat16* __restrict__ emsg,
    float* __restrict__ pos_out) {
  __shared__ __align__(16) __hip_bfloat16 A2[64 * 264];  // hidden -> msg tile
  __shared__ float relb[64][3];
  __shared__ int srow[64], scol[64];
  __shared__ float red[8][64], redsq[8][64];
  __shared__ float mv[64][2];
  __shared__ float gb[HH], btb[HH], cb1b[128], cw2b[128];

  const int tid = threadIdx.x, w = tid >> 6, l = tid & 63, r = l & 15, g = l >> 4;
  const int e0 = blockIdx.x * 64;
  const int chalf = w >> 2;

  // per-lane edge meta (no LDS dependency -> loads issue immediately)
  const int eloc = (w & 3) * 16 + r;
  const int eg = e0 + eloc;
  const int nr = ei[eg], nc = ei[EE + eg];
  float dx = pos[nc * 3 + 0] - pos[nr * 3 + 0] + 1e-8f;
  float dy = pos[nc * 3 + 1] - pos[nr * 3 + 1] + 1e-8f;
  float dz = pos[nc * 3 + 2] - pos[nr * 3 + 2] + 1e-8f;
  float d = sqrtf(dx * dx + dy * dy + dz * dz);
  bf16x8 sfrag;
#pragma unroll
  for (int j = 0; j < 8; ++j) {
    float x = d * rb_w1[g * 8 + j] + rb_b1[g * 8 + j];
    sfrag[j] = (__bf16)silu_f(x);
  }

  // preamble LDS (consumed after first sync)
  if (tid < 256) {
    gb[tid] = en_g[tid];
    btb[tid] = en_bt[tid];
  }
  if (tid < 128) {
    cb1b[tid] = cn_b1[tid];
    cw2b[tid] = cn_w2[tid];
  }
  if (tid < 64) {
    int e = e0 + tid;
    int r2 = ei[e], c2 = ei[EE + e];
    srow[tid] = r2;
    scol[tid] = c2;
    relb[tid][0] = pos[c2 * 3 + 0] - pos[r2 * 3 + 0];
    relb[tid][1] = pos[c2 * 3 + 1] - pos[r2 * 3 + 1];
    relb[tid][2] = pos[c2 * 3 + 2] - pos[r2 * 3 + 2];
  }

  // ---- Phase B: hidden[e][c] = silu(rad + P1 + P2 + b1p), lane-local ----
  const unsigned short* Pu = (const unsigned short*)Pb;
  unsigned short* A2u = (unsigned short*)A2;
#pragma unroll
  for (int t = 0; t < 8; ++t) {
    int cblk = chalf * 8 + t;
    int cbase = cblk * 16 + g * 4;
    bf16x8 afr = *(const bf16x8*)(RWT + (size_t)(cblk * 16 + r) * 32 + g * 8);
    f32x4 rad = __builtin_amdgcn_mfma_f32_16x16x32_bf16(afr, sfrag,
                                                        (f32x4){0.f, 0.f, 0.f, 0.f}, 0, 0, 0);
    ushort4 p1 = *(const ushort4*)(Pu + (size_t)nr * 512 + cbase);
    ushort4 p2 = *(const ushort4*)(Pu + (size_t)nc * 512 + 256 + cbase);
    float4 b1v = *(const float4*)(b1p + cbase);
    ushort4 o;
    o.x = bf_bits(silu_f(rad[0] + ubf(p1.x) + ubf(p2.x) + b1v.x));
    o.y = bf_bits(silu_f(rad[1] + ubf(p1.y) + ubf(p2.y) + b1v.y));
    o.z = bf_bits(silu_f(rad[2] + ubf(p1.z) + ubf(p2.z) + b1v.z));
    o.w = bf_bits(silu_f(rad[3] + ubf(p1.w) + ubf(p2.w) + b1v.w));
    *(ushort4*)(A2u + (size_t)eloc * 264 + cbase) = o;
  }
  __syncthreads();

  // ---- GEMM2: K=256, A from LDS, B direct global ----
  f32x4 acc[4][2];
#pragma unroll
  for (int a = 0; a < 4; ++a)
#pragma unroll
    for (int b = 0; b < 2; ++b) acc[a][b] = (f32x4){0.f, 0.f, 0.f, 0.f};
  for (int ks = 0; ks < 8; ++ks) {
    bf16x8 af[4], bfr[2];
#pragma unroll
    for (int fm = 0; fm < 4; ++fm)
      af[fm] = *(const bf16x8*)(A2 + (fm * 16 + r) * 264 + ks * 32 + g * 8);
#pragma unroll
    for (int fn = 0; fn < 2; ++fn)
      bfr[fn] = *(const bf16x8*)(W2T + (size_t)(w * 32 + fn * 16 + r) * 256 + ks * 32 + g * 8);
#pragma unroll
    for (int fm = 0; fm < 4; ++fm)
#pragma unroll
      for (int fn = 0; fn < 2; ++fn)
        acc[fm][fn] =
            __builtin_amdgcn_mfma_f32_16x16x32_bf16(af[fm], bfr[fn], acc[fm][fn], 0, 0, 0);
  }
#pragma unroll
  for (int fn = 0; fn < 2; ++fn) {
    float b2 = en_b2[w * 32 + fn * 16 + r];
#pragma unroll
    for (int fm = 0; fm < 4; ++fm)
#pragma unroll
      for (int q = 0; q < 4; ++q) acc[fm][fn][q] += b2;
  }

  // LayerNorm stats
#pragma unroll
  for (int fm = 0; fm < 4; ++fm)
#pragma unroll
    for (int q = 0; q < 4; ++q) {
      float s = acc[fm][0][q] + acc[fm][1][q];
      float sq = acc[fm][0][q] * acc[fm][0][q] + acc[fm][1][q] * acc[fm][1][q];
#pragma unroll
      for (int m = 1; m < 16; m <<= 1) {
        s += __shfl_xor(s, m, 64);
        sq += __shfl_xor(sq, m, 64);
      }
      if (r == 0) {
        red[w][fm * 16 + g * 4 + q] = s;
        redsq[w][fm * 16 + g * 4 + q] = sq;
      }
    }
  __syncthreads();
  if (tid < 64) {
    float s = 0.f, sq = 0.f;
#pragma unroll
    for (int k = 0; k < 8; ++k) {
      s += red[k][tid];
      sq += redsq[k][tid];
    }
    float mean = s * (1.0f / HH);
    float var = sq * (1.0f / HH) - mean * mean;
    mv[tid][0] = mean;
    mv[tid][1] = rsqrtf(var + 1e-5f);
  }
  __syncthreads();
#pragma unroll
  for (int fn = 0; fn < 2; ++fn) {
    int col = w * 32 + fn * 16 + r;
    float gg = gb[col], bb = btb[col];
#pragma unroll
    for (int fm = 0; fm < 4; ++fm)
#pragma unroll
      for (int q = 0; q < 4; ++q) {
        int row = fm * 16 + g * 4 + q;
        A2[row * 264 + col] =
            __float2bfloat16((acc[fm][fn][q] - mv[row][0]) * mv[row][1] * gg + bb);
      }
  }
  __syncthreads();

  // store edge_msg (coalesced 16B)
#pragma unroll
  for (int it = 0; it < 4; ++it) {
    int ch = it * 512 + tid;
    int i = ch >> 5, c = ch & 31;
    *(float4*)(emsg + (size_t)(e0 + i) * HH + c * 8) = *(const float4*)(A2 + i * 264 + c * 8);
  }

  // ---- coord head ----
  f32x4 c2a[4];
#pragma unroll
  for (int a = 0; a < 4; ++a) c2a[a] = (f32x4){0.f, 0.f, 0.f, 0.f};
  for (int ks = 0; ks < 8; ++ks) {
    bf16x8 af[4];
#pragma unroll
    for (int fm = 0; fm < 4; ++fm)
      af[fm] = *(const bf16x8*)(A2 + (fm * 16 + r) * 264 + ks * 32 + g * 8);
    bf16x8 bfr = *(const bf16x8*)(CW1T + (size_t)(w * 16 + r) * 256 + ks * 32 + g * 8);
#pragma unroll
    for (int fm = 0; fm < 4; ++fm)
      c2a[fm] = __builtin_amdgcn_mfma_f32_16x16x32_bf16(af[fm], bfr, c2a[fm], 0, 0, 0);
  }
  {
    int ccol = w * 16 + r;
    float cb = cb1b[ccol], cw = cw2b[ccol];
#pragma unroll
    for (int fm = 0; fm < 4; ++fm)
#pragma unroll
      for (int q = 0; q < 4; ++q) {
        float v = silu_f(c2a[fm][q] + cb) * cw;
#pragma unroll
        for (int m = 1; m < 16; m <<= 1) v += __shfl_xor(v, m, 64);
        if (r == 0) red[w][fm * 16 + g * 4 + q] = v;  // reuse red as coord partials
      }
  }
  __syncthreads();
  if (tid < 64) {
    float s = cn_b2[0];
#pragma unroll
    for (int k = 0; k < 8; ++k) s += red[k][tid];
    float wgt = tanhf(s);
    float ax = relb[tid][0], ay = relb[tid][1], az = relb[tid][2];
    int rr = srow[tid], cc = scol[tid];
    atomicAdd(&pos_out[rr * 3 + 0], -wgt * ax);
    atomicAdd(&pos_out[rr * 3 + 1], -wgt * ay);
    atomicAdd(&pos_out[rr * 3 + 2], -wgt * az);
    atomicAdd(&pos_out[cc * 3 + 0], wgt * ax);
    atomicAdd(&pos_out[cc * 3 + 1], wgt * ay);
    atomicAdd(&pos_out[cc * 3 + 2], wgt * az);
  }
}

// ---------------- node_msg = segment_sum(edge_msg, col) via CSR, bf16 out ----------------
__global__ __launch_bounds__(256) void nodemsg_kernel(const int* __restrict__ offs,
                                                      const int* __restrict__ elist,
                                                      const __hip_bfloat16* __restrict__ emsg,
                                                      __hip_bfloat16* __restrict__ nmsgb) {
  int wid = threadIdx.x >> 6, l = threadIdx.x & 63;
  int n = blockIdx.x * 4 + wid;
  float a0 = 0.f, a1 = 0.f, a2 = 0.f, a3 = 0.f;
  int b = offs[n], e2 = offs[n + 1];
  const unsigned short* E = (const unsigned short*)emsg;
  int idx = b;
  for (; idx + 1 < e2; idx += 2) {
    int ea = elist[idx], eb = elist[idx + 1];
    ushort4 va = *(const ushort4*)(E + (size_t)ea * HH + l * 4);
    ushort4 vb = *(const ushort4*)(E + (size_t)eb * HH + l * 4);
    a0 += ubf(va.x) + ubf(vb.x);
    a1 += ubf(va.y) + ubf(vb.y);
    a2 += ubf(va.z) + ubf(vb.z);
    a3 += ubf(va.w) + ubf(vb.w);
  }
  if (idx < e2) {
    int ea = elist[idx];
    ushort4 va = *(const ushort4*)(E + (size_t)ea * HH + l * 4);
    a0 += ubf(va.x);
    a1 += ubf(va.y);
    a2 += ubf(va.z);
    a3 += ubf(va.w);
  }
  ushort4 o;
  o.x = bf_bits(a0);
  o.y = bf_bits(a1);
  o.z = bf_bits(a2);
  o.w = bf_bits(a3);
  *(ushort4*)((unsigned short*)nmsgb + (size_t)n * HH + l * 4) = o;
}

// ---------------- fused node kernel: 32 nodes/block, 8 waves ----------------
__global__ __launch_bounds__(512, 4) void node_kernel(
    const __hip_bfloat16* __restrict__ hb, const __hip_bfloat16* __restrict__ nmsgb,
    const __hip_bfloat16* __restrict__ NW1T, const float* __restrict__ nn_b1,
    const __hip_bfloat16* __restrict__ NW2T, const float* __restrict__ nn_b2,
    const float* __restrict__ nn_g, const float* __restrict__ nn_bt,
    float* __restrict__ out_h) {
  __shared__ __align__(16) __hip_bfloat16 A2[32 * 264];
  __shared__ float red[8][32], redsq[8][32];
  __shared__ float mv[32][2];
  __shared__ float gb[HH], btb[HH];
  const int tid = threadIdx.x, w = tid >> 6, l = tid & 63, r = l & 15, g = l >> 4;
  const int n0 = blockIdx.x * 32;
  if (tid < 256) {
    gb[tid] = nn_g[tid];
    btb[tid] = nn_bt[tid];
  }

  f32x4 acc[2][2];
#pragma unroll
  for (int a = 0; a < 2; ++a)
#pragma unroll
    for (int b = 0; b < 2; ++b) acc[a][b] = (f32x4){0.f, 0.f, 0.f, 0.f};
  for (int ks = 0; ks < 8; ++ks) {
    bf16x8 af[2], bfr[2];
#pragma unroll
    for (int fm = 0; fm < 2; ++fm)
      af[fm] = *(const bf16x8*)(hb + (size_t)(n0 + fm * 16 + r) * 256 + ks * 32 + g * 8);
#pragma unroll
    for (int fn = 0; fn < 2; ++fn)
      bfr[fn] = *(const bf16x8*)(NW1T + (size_t)(w * 32 + fn * 16 + r) * 512 + ks * 32 + g * 8);
#pragma unroll
    for (int fm = 0; fm < 2; ++fm)
#pragma unroll
      for (int fn = 0; fn < 2; ++fn)
        acc[fm][fn] =
            __builtin_amdgcn_mfma_f32_16x16x32_bf16(af[fm], bfr[fn], acc[fm][fn], 0, 0, 0);
  }
  for (int ks = 0; ks < 8; ++ks) {
    bf16x8 af[2], bfr[2];
#pragma unroll
    for (int fm = 0; fm < 2; ++fm)
      af[fm] = *(const bf16x8*)(nmsgb + (size_t)(n0 + fm * 16 + r) * 256 + ks * 32 + g * 8);
#pragma unroll
    for (int fn = 0; fn < 2; ++fn)
      bfr[fn] =
          *(const bf16x8*)(NW1T + (size_t)(w * 32 + fn * 16 + r) * 512 + 256 + ks * 32 + g * 8);
#pragma unroll
    for (int fm = 0; fm < 2; ++fm)
#pragma unroll
      for (int fn = 0; fn < 2; ++fn)
        acc[fm][fn] =
            __builtin_amdgcn_mfma_f32_16x16x32_bf16(af[fm], bfr[fn], acc[fm][fn], 0, 0, 0);
  }
  __syncthreads();
#pragma unroll
  for (int fn = 0; fn < 2; ++fn) {
    int col = w * 32 + fn * 16 + r;
    float b1 = nn_b1[col];
#pragma unroll
    for (int fm = 0; fm < 2; ++fm)
#pragma unroll
      for (int q = 0; q < 4; ++q) {
        int row = fm * 16 + g * 4 + q;
        A2[row * 264 + col] = __float2bfloat16(silu_f(acc[fm][fn][q] + b1));
      }
  }
  __syncthreads();

#pragma unroll
  for (int a = 0; a < 2; ++a)
#pragma unroll
    for (int b = 0; b < 2; ++b) acc[a][b] = (f32x4){0.f, 0.f, 0.f, 0.f};
  for (int ks = 0; ks < 8; ++ks) {
    bf16x8 af[2], bfr[2];
#pragma unroll
    for (int fm = 0; fm < 2; ++fm)
      af[fm] = *(const bf16x8*)(A2 + (fm * 16 + r) * 264 + ks * 32 + g * 8);
#pragma unroll
    for (int fn = 0; fn < 2; ++fn)
      bfr[fn] = *(const bf16x8*)(NW2T + (size_t)(w * 32 + fn * 16 + r) * 256 + ks * 32 + g * 8);
#pragma unroll
    for (int fm = 0; fm < 2; ++fm)
#pragma unroll
      for (int fn = 0; fn < 2; ++fn)
        acc[fm][fn] =
            __builtin_amdgcn_mfma_f32_16x16x32_bf16(af[fm], bfr[fn], acc[fm][fn], 0, 0, 0);
  }
#pragma unroll
  for (int fn = 0; fn < 2; ++fn) {
    float b2 = nn_b2[w * 32 + fn * 16 + r];
#pragma unroll
    for (int fm = 0; fm < 2; ++fm)
#pragma unroll
      for (int q = 0; q < 4; ++q) acc[fm][fn][q] += b2;
  }
#pragma unroll
  for (int fm = 0; fm < 2; ++fm)
#pragma unroll
    for (int q = 0; q < 4; ++q) {
      float s = acc[fm][0][q] + acc[fm][1][q];
      float sq = acc[fm][0][q] * acc[fm][0][q] + acc[fm][1][q] * acc[fm][1][q];
#pragma unroll
      for (int m = 1; m < 16; m <<= 1) {
        s += __shfl_xor(s, m, 64);
        sq += __shfl_xor(sq, m, 64);
      }
      if (r == 0) {
        red[w][fm * 16 + g * 4 + q] = s;
        redsq[w][fm * 16 + g * 4 + q] = sq;
      }
    }
  __syncthreads();
  if (tid < 32) {
    float s = 0.f, sq = 0.f;
#pragma unroll
    for (int k = 0; k < 8; ++k) {
      s += red[k][tid];
      sq += redsq[k][tid];
    }
    float mean = s * (1.0f / HH);
    float var = sq * (1.0f / HH) - mean * mean;
    mv[tid][0] = mean;
    mv[tid][1] = rsqrtf(var + 1e-5f);
  }
  __syncthreads();
#pragma unroll
  for (int fn = 0; fn < 2; ++fn) {
    int col = w * 32 + fn * 16 + r;
    float gg = gb[col], bb = btb[col];
#pragma unroll
    for (int fm = 0; fm < 2; ++fm)
#pragma unroll
      for (int q = 0; q < 4; ++q) {
        int row = fm * 16 + g * 4 + q;
        out_h[(size_t)(n0 + row) * HH + col] =
            (acc[fm][fn][q] - mv[row][0]) * mv[row][1] * gg + bb;
      }
  }
}

// ---------------- launch ----------------
extern "C" void kernel_launch(void* const* d_in, const int* in_sizes, int n_in,
                              void* d_out, int out_size, void* d_ws, size_t ws_size,
                              hipStream_t stream) {
  const float* h = (const float*)d_in[0];
  const float* pos = (const float*)d_in[1];
  const float* rb_w1 = (const float*)d_in[2];
  const float* rb_b1 = (const float*)d_in[3];
  const float* rb_w2 = (const float*)d_in[4];
  const float* rb_b2 = (const float*)d_in[5];
  const float* en_w1 = (const float*)d_in[6];
  const float* en_b1 = (const float*)d_in[7];
  const float* en_w2 = (const float*)d_in[8];
  const float* en_b2 = (const float*)d_in[9];
  const float* en_g = (const float*)d_in[10];
  const float* en_bt = (const float*)d_in[11];
  const float* nn_w1 = (const float*)d_in[12];
  const float* nn_b1 = (const float*)d_in[13];
  const float* nn_w2 = (const float*)d_in[14];
  const float* nn_b2 = (const float*)d_in[15];
  const float* nn_g = (const float*)d_in[16];
  const float* nn_bt = (const float*)d_in[17];
  const float* cn_w1 = (const float*)d_in[18];
  const float* cn_b1 = (const float*)d_in[19];
  const float* cn_w2 = (const float*)d_in[20];
  const float* cn_b2 = (const float*)d_in[21];
  const int* ei = (const int*)d_in[22];

  float* out_h = (float*)d_out;
  float* out_pos = out_h + (size_t)NN * HH;

  char* p = (char*)d_ws;
  auto alloc = [&p](size_t bytes) {
    char* q = p;
    p += (bytes + 255) & ~(size_t)255;
    return q;
  };
  __hip_bfloat16* hb = (__hip_bfloat16*)alloc((size_t)NN * HH * 2);
  __hip_bfloat16* Pb = (__hip_bfloat16*)alloc((size_t)NN * 512 * 2);
  __hip_bfloat16* W1abT = (__hip_bfloat16*)alloc((size_t)512 * 256 * 2);
  __hip_bfloat16* W2T = (__hip_bfloat16*)alloc((size_t)256 * 256 * 2);
  __hip_bfloat16* NW1T = (__hip_bfloat16*)alloc((size_t)256 * 512 * 2);
  __hip_bfloat16* NW2T = (__hip_bfloat16*)alloc((size_t)256 * 256 * 2);
  __hip_bfloat16* CW1T = (__hip_bfloat16*)alloc((size_t)128 * 256 * 2);
  __hip_bfloat16* RWT = (__hip_bfloat16*)alloc((size_t)256 * 32 * 2);
  float* b1p = (float*)alloc((size_t)256 * 4);
  __hip_bfloat16* emsg = (__hip_bfloat16*)alloc((size_t)EE * HH * 2);
  __hip_bfloat16* nmsgb = (__hip_bfloat16*)alloc((size_t)NN * HH * 2);
  int* counts = (int*)alloc((size_t)NN * 4);
  int* offs = (int*)alloc((size_t)(NN + 1) * 4);
  int* cursor = (int*)alloc((size_t)NN * 4);
  int* elist = (int*)alloc((size_t)EE * 4);
  int* bsum = (int*)alloc((size_t)64 * 4);
  int* bbase = (int*)alloc((size_t)64 * 4);

  hipMemsetAsync(out_pos, 0, (size_t)NN * 3 * sizeof(float), stream);
  hipMemsetAsync(counts, 0, (size_t)NN * sizeof(int), stream);

  conv_h_kernel<<<(NN * HH / 4 + 255) / 256, 256, 0, stream>>>(h, hb, NN * HH / 4);
  tr_kernel<<<(256 * 256) / 256, 256, 0, stream>>>(en_w2, W2T, 256, 256);
  tr_kernel<<<(512 * 256) / 256, 256, 0, stream>>>(nn_w1, NW1T, 512, 256);
  tr_kernel<<<(256 * 256) / 256, 256, 0, stream>>>(nn_w2, NW2T, 256, 256);
  tr_kernel<<<(256 * 128) / 256, 256, 0, stream>>>(cn_w1, CW1T, 256, 128);
  tr_kernel<<<(256 * 256) / 256, 256, 0, stream>>>(en_w1, W1abT, 256, 256);
  tr_kernel<<<(256 * 256) / 256, 256, 0, stream>>>(en_w1 + 256 * 256, W1abT + 256 * 256, 256,
                                                   256);
  rwt_kernel<<<(256 * 32) / 256, 256, 0, stream>>>(rb_w2, en_w1, RWT);
  b1p_kernel<<<1, 256, 0, stream>>>(en_b1, rb_b2, en_w1, b1p);
  count_kernel<<<EE / 256, 256, 0, stream>>>(ei, counts);
  scanA_kernel<<<NN / 256, 256, 0, stream>>>(counts, bsum);
  scanB_kernel<<<1, 64, 0, stream>>>(bsum, bbase, offs);
  scanC_kernel<<<NN / 256, 256, 0, stream>>>(counts, bbase, offs, cursor);
  scatter_kernel<<<EE / 256, 256, 0, stream>>>(ei, cursor, elist);
  pgemm_kernel<<<NN / 64, 512, 0, stream>>>(hb, W1abT, Pb);
  edge_kernel<<<EE / 64, 512, 0, stream>>>(Pb, ei, pos, rb_w1, rb_b1, RWT, b1p, W2T, en_b2,
                                           en_g, en_bt, CW1T, cn_b1, cn_w2, cn_b2, emsg,
                                           out_pos);
  nodemsg_kernel<<<NN / 4, 256, 0, stream>>>(offs, elist, emsg, nmsgb);
  node_kernel<<<NN / 32, 512, 0, stream>>>(hb, nmsgb, NW1T, nn_b1, NW2T, nn_b2, nn_g, nn_bt,
                                           out_h);
}

// Round 4
// 513.002 us; speedup vs baseline: 1.7046x; 1.0164x over previous
//
#include <hip/hip_runtime.h>
#include <hip/hip_bf16.h>

// ---------------------------------------------------------------------------
// EGNN layer, v4: CSR-ordered edges, hybrid front-end (transposed rad-MFMA +
// coalesced 16B Psum staging), transposed GEMM2 with in-lane LN + packed
// ushort4 apply-writes, contiguous nodemsg.
// ---------------------------------------------------------------------------

#define NN 16384
#define EE 262144
#define HH 256
#define RR 32

typedef __bf16 bf16x8 __attribute__((ext_vector_type(8)));
typedef float f32x4 __attribute__((ext_vector_type(4)));

__device__ __forceinline__ float silu_f(float x) { return x / (1.0f + __expf(-x)); }

__device__ __forceinline__ unsigned short bf_bits(float x) {
  union { __hip_bfloat16 b; unsigned short u; } v;
  v.b = __float2bfloat16(x);
  return v.u;
}
__device__ __forceinline__ float ubf(unsigned short u) {
  return __uint_as_float(((unsigned)u) << 16);
}

// ---------------- prep ----------------
__global__ __launch_bounds__(256) void conv_h_kernel(const float* __restrict__ src,
                                                     __hip_bfloat16* __restrict__ dst,
                                                     int n4) {
  int i = blockIdx.x * 256 + threadIdx.x;
  if (i >= n4) return;
  float4 v = ((const float4*)src)[i];
  __hip_bfloat16* d = dst + (size_t)i * 4;
  d[0] = __float2bfloat16(v.x);
  d[1] = __float2bfloat16(v.y);
  d[2] = __float2bfloat16(v.z);
  d[3] = __float2bfloat16(v.w);
}

// in [K][Nc] f32 -> out[c*K + k] bf16  (n-major, k-contiguous)
__global__ __launch_bounds__(256) void tr_kernel(const float* __restrict__ in,
                                                 __hip_bfloat16* __restrict__ out,
                                                 int K, int Nc) {
  int i = blockIdx.x * 256 + threadIdx.x;
  if (i >= K * Nc) return;
  int k = i / Nc, c = i - k * Nc;
  out[(size_t)c * K + k] = __float2bfloat16(in[i]);
}

// RWT[c][i] = sum_j rb_w2[i][j] * en_w1[512+j][c]   ([256][32] bf16)
__global__ __launch_bounds__(256) void rwt_kernel(const float* __restrict__ rb_w2,
                                                  const float* __restrict__ en_w1,
                                                  __hip_bfloat16* __restrict__ RWT) {
  int t = blockIdx.x * 256 + threadIdx.x;
  if (t >= 256 * 32) return;
  int c = t >> 5, i = t & 31;
  float s = 0.f;
#pragma unroll
  for (int j = 0; j < 32; ++j) s += rb_w2[i * 32 + j] * en_w1[(512 + j) * 256 + c];
  RWT[c * 32 + i] = __float2bfloat16(s);
}

// b1p[c] = en_b1[c] + sum_j rb_b2[j] * en_w1[512+j][c]
__global__ __launch_bounds__(256) void b1p_kernel(const float* __restrict__ en_b1,
                                                  const float* __restrict__ rb_b2,
                                                  const float* __restrict__ en_w1,
                                                  float* __restrict__ b1p) {
  int c = blockIdx.x * 256 + threadIdx.x;
  if (c >= 256) return;
  float s = en_b1[c];
#pragma unroll
  for (int j = 0; j < 32; ++j) s += rb_b2[j] * en_w1[(512 + j) * 256 + c];
  b1p[c] = s;
}

// ---------------- CSR build (col) ----------------
__global__ __launch_bounds__(256) void count_kernel(const int* __restrict__ ei,
                                                    int* __restrict__ counts) {
  int e = blockIdx.x * 256 + threadIdx.x;
  if (e >= EE) return;
  atomicAdd(&counts[ei[EE + e]], 1);
}

__global__ __launch_bounds__(256) void scanA_kernel(const int* __restrict__ counts,
                                                    int* __restrict__ bsum) {
  __shared__ int ws[4];
  int t = threadIdx.x;
  int v = counts[blockIdx.x * 256 + t];
#pragma unroll
  for (int m = 1; m < 64; m <<= 1) v += __shfl_xor(v, m, 64);
  if ((t & 63) == 0) ws[t >> 6] = v;
  __syncthreads();
  if (t == 0) bsum[blockIdx.x] = ws[0] + ws[1] + ws[2] + ws[3];
}

__global__ __launch_bounds__(64) void scanB_kernel(const int* __restrict__ bsum,
                                                   int* __restrict__ bbase,
                                                   int* __restrict__ offs) {
  int t = threadIdx.x;
  int v = bsum[t], x = v;
#pragma unroll
  for (int d = 1; d < 64; d <<= 1) {
    int y = __shfl_up(x, d, 64);
    if (t >= d) x += y;
  }
  bbase[t] = x - v;
  if (t == 63) offs[NN] = x;
}

__global__ __launch_bounds__(256) void scanC_kernel(const int* __restrict__ counts,
                                                    const int* __restrict__ bbase,
                                                    int* __restrict__ offs,
                                                    int* __restrict__ cursor) {
  __shared__ int wtot[4];
  int t = threadIdx.x, wv = t >> 6, ln = t & 63;
  int base = blockIdx.x * 256;
  int v = counts[base + t], x = v;
#pragma unroll
  for (int d = 1; d < 64; d <<= 1) {
    int y = __shfl_up(x, d, 64);
    if (ln >= d) x += y;
  }
  if (ln == 63) wtot[wv] = x;
  __syncthreads();
  int add = bbase[blockIdx.x];
  for (int k = 0; k < wv; ++k) add += wtot[k];
  int excl = add + x - v;
  offs[base + t] = excl;
  cursor[base + t] = excl;
}

__global__ __launch_bounds__(256) void scatter_kernel(const int* __restrict__ ei,
                                                      int* __restrict__ cursor,
                                                      int* __restrict__ elist) {
  int e = blockIdx.x * 256 + threadIdx.x;
  if (e >= EE) return;
  int c = ei[EE + e];
  int p = atomicAdd(&cursor[c], 1);
  elist[p] = e;
}

// ---------------- P = h @ [W1a|W1b] : [N,512] bf16 ----------------
__global__ __launch_bounds__(512) void pgemm_kernel(const __hip_bfloat16* __restrict__ A,
                                                    const __hip_bfloat16* __restrict__ BT,
                                                    __hip_bfloat16* __restrict__ out) {
  const int tid = threadIdx.x, w = tid >> 6, l = tid & 63, r = l & 15, g = l >> 4;
  const int n0 = blockIdx.x * 64;
  f32x4 acc[4][4];
#pragma unroll
  for (int a = 0; a < 4; ++a)
#pragma unroll
    for (int b = 0; b < 4; ++b) acc[a][b] = (f32x4){0.f, 0.f, 0.f, 0.f};
  for (int ks = 0; ks < 8; ++ks) {
    bf16x8 af[4], bfr[4];
#pragma unroll
    for (int fm = 0; fm < 4; ++fm)
      af[fm] = *(const bf16x8*)(A + (size_t)(n0 + fm * 16 + r) * 256 + ks * 32 + g * 8);
#pragma unroll
    for (int fn = 0; fn < 4; ++fn)
      bfr[fn] = *(const bf16x8*)(BT + (size_t)(w * 64 + fn * 16 + r) * 256 + ks * 32 + g * 8);
#pragma unroll
    for (int fm = 0; fm < 4; ++fm)
#pragma unroll
      for (int fn = 0; fn < 4; ++fn)
        acc[fm][fn] =
            __builtin_amdgcn_mfma_f32_16x16x32_bf16(af[fm], bfr[fn], acc[fm][fn], 0, 0, 0);
  }
#pragma unroll
  for (int fm = 0; fm < 4; ++fm)
#pragma unroll
    for (int fn = 0; fn < 4; ++fn) {
      int col = w * 64 + fn * 16 + r;
#pragma unroll
      for (int q = 0; q < 4; ++q) {
        int row = n0 + fm * 16 + g * 4 + q;
        out[(size_t)row * 512 + col] = __float2bfloat16(acc[fm][fn][q]);
      }
    }
}

// ---------------- fused edge kernel (CSR order) ----------------
// 64 CSR slots/block, 512 threads (8 waves).
__global__ __launch_bounds__(512, 4) void edge_kernel(
    const __hip_bfloat16* __restrict__ Pb, const int* __restrict__ ei,
    const float* __restrict__ pos, const float* __restrict__ rb_w1,
    const float* __restrict__ rb_b1, const __hip_bfloat16* __restrict__ RWT,
    const float* __restrict__ b1p, const __hip_bfloat16* __restrict__ W2T,
    const float* __restrict__ en_b2, const float* __restrict__ en_g,
    const float* __restrict__ en_bt, const __hip_bfloat16* __restrict__ CW1T,
    const float* __restrict__ cn_b1, const float* __restrict__ cn_w2,
    const float* __restrict__ cn_b2, const int* __restrict__ elist,
    __hip_bfloat16* __restrict__ emsg, float* __restrict__ pos_out) {
  __shared__ __align__(16) __hip_bfloat16 A2[64 * 264];  // rad -> hidden -> msg
  __shared__ float relb[64][3];
  __shared__ float distb[64];
  __shared__ int srow[64], scol[64];
  __shared__ float red[8][64], redsq[8][64];
  __shared__ float mv[64][2];
  __shared__ float cb1b[128], cw2b[128];

  const int tid = threadIdx.x, w = tid >> 6, l = tid & 63, r = l & 15, g = l >> 4;
  const int e0 = blockIdx.x * 64;

  if (tid < 128) {
    cb1b[tid] = cn_b1[tid];
    cw2b[tid] = cn_w2[tid];
  }
  if (tid < 64) {
    int e = elist[e0 + tid];
    int r2 = ei[e], c2 = ei[EE + e];
    srow[tid] = r2;
    scol[tid] = c2;
    float dx = pos[c2 * 3 + 0] - pos[r2 * 3 + 0];
    float dy = pos[c2 * 3 + 1] - pos[r2 * 3 + 1];
    float dz = pos[c2 * 3 + 2] - pos[r2 * 3 + 2];
    relb[tid][0] = dx;
    relb[tid][1] = dy;
    relb[tid][2] = dz;
    float ex = dx + 1e-8f, ey = dy + 1e-8f, ez = dz + 1e-8f;
    distb[tid] = sqrtf(ex * ex + ey * ey + ez * ez);
  }
  __syncthreads();  // #1: meta ready

  // ---- rad pre-pass (transposed MFMA), packed bf16 writes into A2 ----
  unsigned short* A2u = (unsigned short*)A2;
  {
    const int eloc = (w & 3) * 16 + r;
    const int chalf = w >> 2;
    float d = distb[eloc];
    bf16x8 sfrag;
#pragma unroll
    for (int j = 0; j < 8; ++j) {
      float x = d * rb_w1[g * 8 + j] + rb_b1[g * 8 + j];
      sfrag[j] = (__bf16)silu_f(x);
    }
#pragma unroll
    for (int t = 0; t < 8; ++t) {
      int cblk = chalf * 8 + t;
      int cbase = cblk * 16 + g * 4;
      bf16x8 afr = *(const bf16x8*)(RWT + (size_t)(cblk * 16 + r) * 32 + g * 8);
      f32x4 rad = __builtin_amdgcn_mfma_f32_16x16x32_bf16(
          afr, sfrag, (f32x4){0.f, 0.f, 0.f, 0.f}, 0, 0, 0);
      ushort4 o;
      o.x = bf_bits(rad[0]);
      o.y = bf_bits(rad[1]);
      o.z = bf_bits(rad[2]);
      o.w = bf_bits(rad[3]);
      *(ushort4*)(A2u + (size_t)eloc * 264 + cbase) = o;
    }
  }
  __syncthreads();  // #2: rad in A2

  // ---- staging: hidden = silu(rad + P1 + P2 + b1p), coalesced 16B gathers ----
#pragma unroll
  for (int it = 0; it < 4; ++it) {
    int ch = it * 512 + tid;  // 2048 chunks of 8 elems
    int i = ch >> 5, c = ch & 31;
    bf16x8 radv = *(const bf16x8*)(A2 + i * 264 + c * 8);
    bf16x8 p1 = *(const bf16x8*)(Pb + (size_t)srow[i] * 512 + c * 8);
    bf16x8 p2 = *(const bf16x8*)(Pb + (size_t)scol[i] * 512 + 256 + c * 8);
    float4 b1a = *(const float4*)(b1p + c * 8);
    float4 b1b = *(const float4*)(b1p + c * 8 + 4);
    float bv[8] = {b1a.x, b1a.y, b1a.z, b1a.w, b1b.x, b1b.y, b1b.z, b1b.w};
    bf16x8 o;
#pragma unroll
    for (int j = 0; j < 8; ++j)
      o[j] = (__bf16)silu_f((float)radv[j] + (float)p1[j] + (float)p2[j] + bv[j]);
    *(bf16x8*)(A2 + i * 264 + c * 8) = o;
  }
  __syncthreads();  // #3: hidden ready

  // ---- GEMM2 (transposed): D[c'][e], A=W2T rows, B=A2 rows ----
  f32x4 acc[2][4];
#pragma unroll
  for (int a = 0; a < 2; ++a)
#pragma unroll
    for (int b = 0; b < 4; ++b) acc[a][b] = (f32x4){0.f, 0.f, 0.f, 0.f};
  for (int ks = 0; ks < 8; ++ks) {
    bf16x8 af[2], bfr[4];
#pragma unroll
    for (int mf = 0; mf < 2; ++mf)
      af[mf] = *(const bf16x8*)(W2T + (size_t)(w * 32 + mf * 16 + r) * 256 + ks * 32 + g * 8);
#pragma unroll
    for (int nf = 0; nf < 4; ++nf)
      bfr[nf] = *(const bf16x8*)(A2 + (nf * 16 + r) * 264 + ks * 32 + g * 8);
#pragma unroll
    for (int mf = 0; mf < 2; ++mf)
#pragma unroll
      for (int nf = 0; nf < 4; ++nf)
        acc[mf][nf] =
            __builtin_amdgcn_mfma_f32_16x16x32_bf16(af[mf], bfr[nf], acc[mf][nf], 0, 0, 0);
  }
  // bias per c' (row side now)
  {
    float4 b2v0 = *(const float4*)(en_b2 + w * 32 + g * 4);
    float4 b2v1 = *(const float4*)(en_b2 + w * 32 + 16 + g * 4);
#pragma unroll
    for (int nf = 0; nf < 4; ++nf) {
      acc[0][nf][0] += b2v0.x;
      acc[0][nf][1] += b2v0.y;
      acc[0][nf][2] += b2v0.z;
      acc[0][nf][3] += b2v0.w;
      acc[1][nf][0] += b2v1.x;
      acc[1][nf][1] += b2v1.y;
      acc[1][nf][2] += b2v1.z;
      acc[1][nf][3] += b2v1.w;
    }
  }

  // ---- LN stats: per-edge sums (in-lane over mf,q; shfl over g; LDS over waves)
#pragma unroll
  for (int nf = 0; nf < 4; ++nf) {
    float s = 0.f, sq = 0.f;
#pragma unroll
    for (int mf = 0; mf < 2; ++mf)
#pragma unroll
      for (int q = 0; q < 4; ++q) {
        float v = acc[mf][nf][q];
        s += v;
        sq += v * v;
      }
    s += __shfl_xor(s, 16, 64);
    s += __shfl_xor(s, 32, 64);
    sq += __shfl_xor(sq, 16, 64);
    sq += __shfl_xor(sq, 32, 64);
    if (l < 16) {
      red[w][nf * 16 + l] = s;
      redsq[w][nf * 16 + l] = sq;
    }
  }
  __syncthreads();  // #4
  if (tid < 64) {
    float s = 0.f, sq = 0.f;
#pragma unroll
    for (int k = 0; k < 8; ++k) {
      s += red[k][tid];
      sq += redsq[k][tid];
    }
    float mean = s * (1.0f / HH);
    float var = sq * (1.0f / HH) - mean * mean;
    mv[tid][0] = mean;
    mv[tid][1] = rsqrtf(var + 1e-5f);
  }
  __syncthreads();  // #5

  // ---- LN apply: packed ushort4 writes (4 consecutive c' per write) ----
  {
    float4 gv0 = *(const float4*)(en_g + w * 32 + g * 4);
    float4 gv1 = *(const float4*)(en_g + w * 32 + 16 + g * 4);
    float4 bv0 = *(const float4*)(en_bt + w * 32 + g * 4);
    float4 bv1 = *(const float4*)(en_bt + w * 32 + 16 + g * 4);
#pragma unroll
    for (int nf = 0; nf < 4; ++nf) {
      int e = nf * 16 + r;
      float mm = mv[e][0], rs = mv[e][1];
      ushort4 o0, o1;
      o0.x = bf_bits((acc[0][nf][0] - mm) * rs * gv0.x + bv0.x);
      o0.y = bf_bits((acc[0][nf][1] - mm) * rs * gv0.y + bv0.y);
      o0.z = bf_bits((acc[0][nf][2] - mm) * rs * gv0.z + bv0.z);
      o0.w = bf_bits((acc[0][nf][3] - mm) * rs * gv0.w + bv0.w);
      o1.x = bf_bits((acc[1][nf][0] - mm) * rs * gv1.x + bv1.x);
      o1.y = bf_bits((acc[1][nf][1] - mm) * rs * gv1.y + bv1.y);
      o1.z = bf_bits((acc[1][nf][2] - mm) * rs * gv1.z + bv1.z);
      o1.w = bf_bits((acc[1][nf][3] - mm) * rs * gv1.w + bv1.w);
      *(ushort4*)(A2u + (size_t)e * 264 + w * 32 + g * 4) = o0;
      *(ushort4*)(A2u + (size_t)e * 264 + w * 32 + 16 + g * 4) = o1;
    }
  }
  __syncthreads();  // #6: msg ready

  // store edge_msg at CSR position (coalesced 16B)
#pragma unroll
  for (int it = 0; it < 4; ++it) {
    int ch = it * 512 + tid;
    int i = ch >> 5, c = ch & 31;
    *(float4*)(emsg + (size_t)(e0 + i) * HH + c * 8) = *(const float4*)(A2 + i * 264 + c * 8);
  }

  // ---- coord head ----
  f32x4 c2a[4];
#pragma unroll
  for (int a = 0; a < 4; ++a) c2a[a] = (f32x4){0.f, 0.f, 0.f, 0.f};
  for (int ks = 0; ks < 8; ++ks) {
    bf16x8 af[4];
#pragma unroll
    for (int fm = 0; fm < 4; ++fm)
      af[fm] = *(const bf16x8*)(A2 + (fm * 16 + r) * 264 + ks * 32 + g * 8);
    bf16x8 bfr = *(const bf16x8*)(CW1T + (size_t)(w * 16 + r) * 256 + ks * 32 + g * 8);
#pragma unroll
    for (int fm = 0; fm < 4; ++fm)
      c2a[fm] = __builtin_amdgcn_mfma_f32_16x16x32_bf16(af[fm], bfr, c2a[fm], 0, 0, 0);
  }
  {
    int ccol = w * 16 + r;
    float cb = cb1b[ccol], cw = cw2b[ccol];
#pragma unroll
    for (int fm = 0; fm < 4; ++fm)
#pragma unroll
      for (int q = 0; q < 4; ++q) {
        float v = silu_f(c2a[fm][q] + cb) * cw;
#pragma unroll
        for (int m = 1; m < 16; m <<= 1) v += __shfl_xor(v, m, 64);
        if (r == 0) red[w][fm * 16 + g * 4 + q] = v;
      }
  }
  __syncthreads();  // #7
  if (tid < 64) {
    float s = cn_b2[0];
#pragma unroll
    for (int k = 0; k < 8; ++k) s += red[k][tid];
    float wgt = tanhf(s);
    float ax = relb[tid][0], ay = relb[tid][1], az = relb[tid][2];
    int rr = srow[tid], cc = scol[tid];
    atomicAdd(&pos_out[rr * 3 + 0], -wgt * ax);
    atomicAdd(&pos_out[rr * 3 + 1], -wgt * ay);
    atomicAdd(&pos_out[rr * 3 + 2], -wgt * az);
    atomicAdd(&pos_out[cc * 3 + 0], wgt * ax);
    atomicAdd(&pos_out[cc * 3 + 1], wgt * ay);
    atomicAdd(&pos_out[cc * 3 + 2], wgt * az);
  }
}

// ---------------- node_msg: emsg is CSR-ordered -> contiguous row ranges ----------------
__global__ __launch_bounds__(256) void nodemsg_kernel(const int* __restrict__ offs,
                                                      const __hip_bfloat16* __restrict__ emsg,
                                                      __hip_bfloat16* __restrict__ nmsgb) {
  int wid = threadIdx.x >> 6, l = threadIdx.x & 63;
  int n = blockIdx.x * 4 + wid;
  float a0 = 0.f, a1 = 0.f, a2 = 0.f, a3 = 0.f;
  int b = offs[n], e2 = offs[n + 1];
  const unsigned short* E = (const unsigned short*)emsg;
  int p = b;
  for (; p + 1 < e2; p += 2) {
    ushort4 va = *(const ushort4*)(E + (size_t)p * HH + l * 4);
    ushort4 vb = *(const ushort4*)(E + (size_t)(p + 1) * HH + l * 4);
    a0 += ubf(va.x) + ubf(vb.x);
    a1 += ubf(va.y) + ubf(vb.y);
    a2 += ubf(va.z) + ubf(vb.z);
    a3 += ubf(va.w) + ubf(vb.w);
  }
  if (p < e2) {
    ushort4 va = *(const ushort4*)(E + (size_t)p * HH + l * 4);
    a0 += ubf(va.x);
    a1 += ubf(va.y);
    a2 += ubf(va.z);
    a3 += ubf(va.w);
  }
  ushort4 o;
  o.x = bf_bits(a0);
  o.y = bf_bits(a1);
  o.z = bf_bits(a2);
  o.w = bf_bits(a3);
  *(ushort4*)((unsigned short*)nmsgb + (size_t)n * HH + l * 4) = o;
}

// ---------------- fused node kernel: 32 nodes/block, 8 waves ----------------
__global__ __launch_bounds__(512, 4) void node_kernel(
    const __hip_bfloat16* __restrict__ hb, const __hip_bfloat16* __restrict__ nmsgb,
    const __hip_bfloat16* __restrict__ NW1T, const float* __restrict__ nn_b1,
    const __hip_bfloat16* __restrict__ NW2T, const float* __restrict__ nn_b2,
    const float* __restrict__ nn_g, const float* __restrict__ nn_bt,
    float* __restrict__ out_h) {
  __shared__ __align__(16) __hip_bfloat16 A2[32 * 264];
  __shared__ float red[8][32], redsq[8][32];
  __shared__ float mv[32][2];
  __shared__ float gb[HH], btb[HH];
  const int tid = threadIdx.x, w = tid >> 6, l = tid & 63, r = l & 15, g = l >> 4;
  const int n0 = blockIdx.x * 32;
  if (tid < 256) {
    gb[tid] = nn_g[tid];
    btb[tid] = nn_bt[tid];
  }

  f32x4 acc[2][2];
#pragma unroll
  for (int a = 0; a < 2; ++a)
#pragma unroll
    for (int b = 0; b < 2; ++b) acc[a][b] = (f32x4){0.f, 0.f, 0.f, 0.f};
  for (int ks = 0; ks < 8; ++ks) {
    bf16x8 af[2], bfr[2];
#pragma unroll
    for (int fm = 0; fm < 2; ++fm)
      af[fm] = *(const bf16x8*)(hb + (size_t)(n0 + fm * 16 + r) * 256 + ks * 32 + g * 8);
#pragma unroll
    for (int fn = 0; fn < 2; ++fn)
      bfr[fn] = *(const bf16x8*)(NW1T + (size_t)(w * 32 + fn * 16 + r) * 512 + ks * 32 + g * 8);
#pragma unroll
    for (int fm = 0; fm < 2; ++fm)
#pragma unroll
      for (int fn = 0; fn < 2; ++fn)
        acc[fm][fn] =
            __builtin_amdgcn_mfma_f32_16x16x32_bf16(af[fm], bfr[fn], acc[fm][fn], 0, 0, 0);
  }
  for (int ks = 0; ks < 8; ++ks) {
    bf16x8 af[2], bfr[2];
#pragma unroll
    for (int fm = 0; fm < 2; ++fm)
      af[fm] = *(const bf16x8*)(nmsgb + (size_t)(n0 + fm * 16 + r) * 256 + ks * 32 + g * 8);
#pragma unroll
    for (int fn = 0; fn < 2; ++fn)
      bfr[fn] =
          *(const bf16x8*)(NW1T + (size_t)(w * 32 + fn * 16 + r) * 512 + 256 + ks * 32 + g * 8);
#pragma unroll
    for (int fm = 0; fm < 2; ++fm)
#pragma unroll
      for (int fn = 0; fn < 2; ++fn)
        acc[fm][fn] =
            __builtin_amdgcn_mfma_f32_16x16x32_bf16(af[fm], bfr[fn], acc[fm][fn], 0, 0, 0);
  }
  __syncthreads();
#pragma unroll
  for (int fn = 0; fn < 2; ++fn) {
    int col = w * 32 + fn * 16 + r;
    float b1 = nn_b1[col];
#pragma unroll
    for (int fm = 0; fm < 2; ++fm)
#pragma unroll
      for (int q = 0; q < 4; ++q) {
        int row = fm * 16 + g * 4 + q;
        A2[row * 264 + col] = __float2bfloat16(silu_f(acc[fm][fn][q] + b1));
      }
  }
  __syncthreads();

#pragma unroll
  for (int a = 0; a < 2; ++a)
#pragma unroll
    for (int b = 0; b < 2; ++b) acc[a][b] = (f32x4){0.f, 0.f, 0.f, 0.f};
  for (int ks = 0; ks < 8; ++ks) {
    bf16x8 af[2], bfr[2];
#pragma unroll
    for (int fm = 0; fm < 2; ++fm)
      af[fm] = *(const bf16x8*)(A2 + (fm * 16 + r) * 264 + ks * 32 + g * 8);
#pragma unroll
    for (int fn = 0; fn < 2; ++fn)
      bfr[fn] = *(const bf16x8*)(NW2T + (size_t)(w * 32 + fn * 16 + r) * 256 + ks * 32 + g * 8);
#pragma unroll
    for (int fm = 0; fm < 2; ++fm)
#pragma unroll
      for (int fn = 0; fn < 2; ++fn)
        acc[fm][fn] =
            __builtin_amdgcn_mfma_f32_16x16x32_bf16(af[fm], bfr[fn], acc[fm][fn], 0, 0, 0);
  }
#pragma unroll
  for (int fn = 0; fn < 2; ++fn) {
    float b2 = nn_b2[w * 32 + fn * 16 + r];
#pragma unroll
    for (int fm = 0; fm < 2; ++fm)
#pragma unroll
      for (int q = 0; q < 4; ++q) acc[fm][fn][q] += b2;
  }
#pragma unroll
  for (int fm = 0; fm < 2; ++fm)
#pragma unroll
    for (int q = 0; q < 4; ++q) {
      float s = acc[fm][0][q] + acc[fm][1][q];
      float sq = acc[fm][0][q] * acc[fm][0][q] + acc[fm][1][q] * acc[fm][1][q];
#pragma unroll
      for (int m = 1; m < 16; m <<= 1) {
        s += __shfl_xor(s, m, 64);
        sq += __shfl_xor(sq, m, 64);
      }
      if (r == 0) {
        red[w][fm * 16 + g * 4 + q] = s;
        redsq[w][fm * 16 + g * 4 + q] = sq;
      }
    }
  __syncthreads();
  if (tid < 32) {
    float s = 0.f, sq = 0.f;
#pragma unroll
    for (int k = 0; k < 8; ++k) {
      s += red[k][tid];
      sq += redsq[k][tid];
    }
    float mean = s * (1.0f / HH);
    float var = sq * (1.0f / HH) - mean * mean;
    mv[tid][0] = mean;
    mv[tid][1] = rsqrtf(var + 1e-5f);
  }
  __syncthreads();
#pragma unroll
  for (int fn = 0; fn < 2; ++fn) {
    int col = w * 32 + fn * 16 + r;
    float gg = gb[col], bb = btb[col];
#pragma unroll
    for (int fm = 0; fm < 2; ++fm)
#pragma unroll
      for (int q = 0; q < 4; ++q) {
        int row = fm * 16 + g * 4 + q;
        out_h[(size_t)(n0 + row) * HH + col] =
            (acc[fm][fn][q] - mv[row][0]) * mv[row][1] * gg + bb;
      }
  }
}

// ---------------- launch ----------------
extern "C" void kernel_launch(void* const* d_in, const int* in_sizes, int n_in,
                              void* d_out, int out_size, void* d_ws, size_t ws_size,
                              hipStream_t stream) {
  const float* h = (const float*)d_in[0];
  const float* pos = (const float*)d_in[1];
  const float* rb_w1 = (const float*)d_in[2];
  const float* rb_b1 = (const float*)d_in[3];
  const float* rb_w2 = (const float*)d_in[4];
  const float* rb_b2 = (const float*)d_in[5];
  const float* en_w1 = (const float*)d_in[6];
  const float* en_b1 = (const float*)d_in[7];
  const float* en_w2 = (const float*)d_in[8];
  const float* en_b2 = (const float*)d_in[9];
  const float* en_g = (const float*)d_in[10];
  const float* en_bt = (const float*)d_in[11];
  const float* nn_w1 = (const float*)d_in[12];
  const float* nn_b1 = (const float*)d_in[13];
  const float* nn_w2 = (const float*)d_in[14];
  const float* nn_b2 = (const float*)d_in[15];
  const float* nn_g = (const float*)d_in[16];
  const float* nn_bt = (const float*)d_in[17];
  const float* cn_w1 = (const float*)d_in[18];
  const float* cn_b1 = (const float*)d_in[19];
  const float* cn_w2 = (const float*)d_in[20];
  const float* cn_b2 = (const float*)d_in[21];
  const int* ei = (const int*)d_in[22];

  float* out_h = (float*)d_out;
  float* out_pos = out_h + (size_t)NN * HH;

  char* p = (char*)d_ws;
  auto alloc = [&p](size_t bytes) {
    char* q = p;
    p += (bytes + 255) & ~(size_t)255;
    return q;
  };
  __hip_bfloat16* hb = (__hip_bfloat16*)alloc((size_t)NN * HH * 2);
  __hip_bfloat16* Pb = (__hip_bfloat16*)alloc((size_t)NN * 512 * 2);
  __hip_bfloat16* W1abT = (__hip_bfloat16*)alloc((size_t)512 * 256 * 2);
  __hip_bfloat16* W2T = (__hip_bfloat16*)alloc((size_t)256 * 256 * 2);
  __hip_bfloat16* NW1T = (__hip_bfloat16*)alloc((size_t)256 * 512 * 2);
  __hip_bfloat16* NW2T = (__hip_bfloat16*)alloc((size_t)256 * 256 * 2);
  __hip_bfloat16* CW1T = (__hip_bfloat16*)alloc((size_t)128 * 256 * 2);
  __hip_bfloat16* RWT = (__hip_bfloat16*)alloc((size_t)256 * 32 * 2);
  float* b1p = (float*)alloc((size_t)256 * 4);
  __hip_bfloat16* emsg = (__hip_bfloat16*)alloc((size_t)EE * HH * 2);
  __hip_bfloat16* nmsgb = (__hip_bfloat16*)alloc((size_t)NN * HH * 2);
  int* counts = (int*)alloc((size_t)NN * 4);
  int* offs = (int*)alloc((size_t)(NN + 1) * 4);
  int* cursor = (int*)alloc((size_t)NN * 4);
  int* elist = (int*)alloc((size_t)EE * 4);
  int* bsum = (int*)alloc((size_t)64 * 4);
  int* bbase = (int*)alloc((size_t)64 * 4);

  hipMemsetAsync(out_pos, 0, (size_t)NN * 3 * sizeof(float), stream);
  hipMemsetAsync(counts, 0, (size_t)NN * sizeof(int), stream);

  conv_h_kernel<<<(NN * HH / 4 + 255) / 256, 256, 0, stream>>>(h, hb, NN * HH / 4);
  tr_kernel<<<(256 * 256) / 256, 256, 0, stream>>>(en_w2, W2T, 256, 256);
  tr_kernel<<<(512 * 256) / 256, 256, 0, stream>>>(nn_w1, NW1T, 512, 256);
  tr_kernel<<<(256 * 256) / 256, 256, 0, stream>>>(nn_w2, NW2T, 256, 256);
  tr_kernel<<<(256 * 128) / 256, 256, 0, stream>>>(cn_w1, CW1T, 256, 128);
  tr_kernel<<<(256 * 256) / 256, 256, 0, stream>>>(en_w1, W1abT, 256, 256);
  tr_kernel<<<(256 * 256) / 256, 256, 0, stream>>>(en_w1 + 256 * 256, W1abT + 256 * 256, 256,
                                                   256);
  rwt_kernel<<<(256 * 32) / 256, 256, 0, stream>>>(rb_w2, en_w1, RWT);
  b1p_kernel<<<1, 256, 0, stream>>>(en_b1, rb_b2, en_w1, b1p);
  count_kernel<<<EE / 256, 256, 0, stream>>>(ei, counts);
  scanA_kernel<<<NN / 256, 256, 0, stream>>>(counts, bsum);
  scanB_kernel<<<1, 64, 0, stream>>>(bsum, bbase, offs);
  scanC_kernel<<<NN / 256, 256, 0, stream>>>(counts, bbase, offs, cursor);
  scatter_kernel<<<EE / 256, 256, 0, stream>>>(ei, cursor, elist);
  pgemm_kernel<<<NN / 64, 512, 0, stream>>>(hb, W1abT, Pb);
  edge_kernel<<<EE / 64, 512, 0, stream>>>(Pb, ei, pos, rb_w1, rb_b1, RWT, b1p, W2T, en_b2,
                                           en_g, en_bt, CW1T, cn_b1, cn_w2, cn_b2, elist,
                                           emsg, out_pos);
  nodemsg_kernel<<<NN / 4, 256, 0, stream>>>(offs, emsg, nmsgb);
  node_kernel<<<NN / 32, 512, 0, stream>>>(hb, nmsgb, NW1T, nn_b1, NW2T, nn_b2, nn_g, nn_bt,
                                           out_h);
}